// Round 11
// baseline (4839.709 us; speedup 1.0000x reference)
//
#include <hip/hip_runtime.h>
#include <hip/hip_bf16.h>
#include <math.h>

#define B_   32
#define L_   1024
#define CIN_ 64
#define D_   512
#define DFF_ 2048
#define NL_  3
#define TOPK_ 6
#define NBLD_ ((size_t)B_ * L_ * D_)

#define TM 64
#define TN 64
#define TBK 16

typedef unsigned short u16;
typedef __bf16 bf16x8 __attribute__((ext_vector_type(8)));
typedef float  f32x4  __attribute__((ext_vector_type(4)));
typedef unsigned short u16x8 __attribute__((ext_vector_type(8)));

__device__ __forceinline__ float bf2f(u16 u) {
  return __uint_as_float(((unsigned int)u) << 16);
}
__device__ __forceinline__ u16 f2bf(float f) {
  unsigned int u = __float_as_uint(f);
  return (u16)((u + 0x7fffu + ((u >> 16) & 1u)) >> 16);   // RNE
}
// packed split: lo16 of word = bf16(f) [hi part], hi16 of word = bf16(residual)
__device__ __forceinline__ unsigned int split2(float f) {
  u16 hi = f2bf(f);
  u16 lo = f2bf(f - bf2f(hi));
  return (unsigned int)hi | ((unsigned int)lo << 16);
}
__device__ __forceinline__ float gelu_f(float x) {
  return 0.5f * x * (1.0f + erff(x * 0.70710678118654752440f));
}

__global__ __launch_bounds__(256) void zero_k(float* __restrict__ p, int n) {
  int i = blockIdx.x * 256 + threadIdx.x;
  if (i < n) p[i] = 0.f;
}

// ---------------- weight transpose + bf16x2 split ----------------
__global__ __launch_bounds__(256) void transp_split_k(const float* __restrict__ W,
                                                      u16* __restrict__ WTh,
                                                      u16* __restrict__ WTl, int K, int N) {
  __shared__ float tile[32][33];
  const int t = threadIdx.x;
  const int k0 = blockIdx.x * 32, n0 = blockIdx.y * 32;
  const int tx = t & 31, ty = t >> 5;
#pragma unroll
  for (int i = 0; i < 4; ++i) {
    int kk = ty + i * 8;
    tile[kk][tx] = W[(size_t)(k0 + kk) * N + n0 + tx];
  }
  __syncthreads();
#pragma unroll
  for (int i = 0; i < 4; ++i) {
    int nn = ty + i * 8;
    unsigned int s = split2(tile[tx][nn]);
    WTh[(size_t)(n0 + nn) * K + k0 + tx] = (u16)(s & 0xffffu);
    WTl[(size_t)(n0 + nn) * K + k0 + tx] = (u16)(s >> 16);
  }
}

// ---------------- plain bf16 MFMA GEMM (post-selection layer only) ----------------
__global__ __launch_bounds__(256) void mfma_gemm_k(
    const float* __restrict__ A, int lda,
    const u16* __restrict__ WT, int ldwt,
    float* __restrict__ C, int ldc,
    const float* __restrict__ bias,
    const float* __restrict__ R,
    int K, int mode)
{
  __shared__ u16 As[128 * 40];
  __shared__ u16 Bs[128 * 40];
  const int t = threadIdx.x;
  const int m0 = blockIdx.x * 128, n0 = blockIdx.y * 128;
  const int row = t >> 1, half = t & 1;
  const int lane = t & 63, wid = t >> 6;
  const int wm = (wid & 1) * 64, wn = (wid >> 1) * 64;
  const int lm = lane & 15, quad = lane >> 4, k8 = quad * 8;

  f32x4 acc[4][4];
#pragma unroll
  for (int i = 0; i < 4; ++i)
#pragma unroll
    for (int j = 0; j < 4; ++j) acc[i][j] = (f32x4){0.f, 0.f, 0.f, 0.f};

  for (int k0 = 0; k0 < K; k0 += 32) {
    const float* ap = &A[(size_t)(m0 + row) * lda + k0 + half * 16];
    float4 f0 = *(const float4*)(ap + 0);
    float4 f1 = *(const float4*)(ap + 4);
    float4 f2 = *(const float4*)(ap + 8);
    float4 f3 = *(const float4*)(ap + 12);
    const u16* bp = &WT[(size_t)(n0 + row) * ldwt + k0 + half * 16];
    u16x8 b0 = *(const u16x8*)(bp + 0);
    u16x8 b1 = *(const u16x8*)(bp + 8);
    u16x8 a0, a1;
    a0[0] = f2bf(f0.x); a0[1] = f2bf(f0.y); a0[2] = f2bf(f0.z); a0[3] = f2bf(f0.w);
    a0[4] = f2bf(f1.x); a0[5] = f2bf(f1.y); a0[6] = f2bf(f1.z); a0[7] = f2bf(f1.w);
    a1[0] = f2bf(f2.x); a1[1] = f2bf(f2.y); a1[2] = f2bf(f2.z); a1[3] = f2bf(f2.w);
    a1[4] = f2bf(f3.x); a1[5] = f2bf(f3.y); a1[6] = f2bf(f3.z); a1[7] = f2bf(f3.w);
    __syncthreads();
    *(u16x8*)&As[row * 40 + half * 16 + 0] = a0;
    *(u16x8*)&As[row * 40 + half * 16 + 8] = a1;
    *(u16x8*)&Bs[row * 40 + half * 16 + 0] = b0;
    *(u16x8*)&Bs[row * 40 + half * 16 + 8] = b1;
    __syncthreads();

    bf16x8 af[4], bf[4];
#pragma unroll
    for (int mi = 0; mi < 4; ++mi)
      af[mi] = *(const bf16x8*)&As[(wm + mi * 16 + lm) * 40 + k8];
#pragma unroll
    for (int ni = 0; ni < 4; ++ni)
      bf[ni] = *(const bf16x8*)&Bs[(wn + ni * 16 + lm) * 40 + k8];
#pragma unroll
    for (int mi = 0; mi < 4; ++mi)
#pragma unroll
      for (int ni = 0; ni < 4; ++ni)
        acc[mi][ni] = __builtin_amdgcn_mfma_f32_16x16x32_bf16(af[mi], bf[ni], acc[mi][ni], 0, 0, 0);
  }

#pragma unroll
  for (int mi = 0; mi < 4; ++mi) {
#pragma unroll
    for (int ni = 0; ni < 4; ++ni) {
      int gcol = n0 + wn + ni * 16 + lm;
#pragma unroll
      for (int r = 0; r < 4; ++r) {
        int grow = m0 + wm + mi * 16 + quad * 4 + r;
        float v = acc[mi][ni][r];
        size_t ci = (size_t)grow * ldc + gcol;
        if (mode == 1) {
          v = gelu_f(v);
        } else if (mode == 2) {
          v += C[ci];
        } else {
          if (bias) v += bias[gcol];
          if (R) v += R[ci];
        }
        C[ci] = v;
      }
    }
  }
}

// ---------------- bf16x2-split MFMA GEMM (~fp32 precision) ----------------
// mode 0: (+bias)(+R) fp32 store; 1: gelu store; 2: C+= ; 3: (+bias) split-store
// (mode 3: C is u16*; hi at [idx], lo at [idx + NBLD_])
__global__ __launch_bounds__(256) void mfma_split_gemm_k(
    const float* __restrict__ A, int lda,
    const u16* __restrict__ WTh, const u16* __restrict__ WTl, int ldwt,
    float* __restrict__ C, int ldc,
    const float* __restrict__ bias,
    const float* __restrict__ R,
    int K, int mode)
{
  __shared__ u16 Ash[128 * 40];
  __shared__ u16 Asl[128 * 40];
  __shared__ u16 Bsh[128 * 40];
  __shared__ u16 Bsl[128 * 40];
  const int t = threadIdx.x;
  const int m0 = blockIdx.x * 128, n0 = blockIdx.y * 128;
  const int row = t >> 1, half = t & 1;
  const int lane = t & 63, wid = t >> 6;
  const int wm = (wid & 1) * 64, wn = (wid >> 1) * 64;
  const int lm = lane & 15, quad = lane >> 4, k8 = quad * 8;

  f32x4 acc[4][4];
#pragma unroll
  for (int i = 0; i < 4; ++i)
#pragma unroll
    for (int j = 0; j < 4; ++j) acc[i][j] = (f32x4){0.f, 0.f, 0.f, 0.f};

  for (int k0 = 0; k0 < K; k0 += 32) {
    const float* ap = &A[(size_t)(m0 + row) * lda + k0 + half * 16];
    float4 f0 = *(const float4*)(ap + 0);
    float4 f1 = *(const float4*)(ap + 4);
    float4 f2 = *(const float4*)(ap + 8);
    float4 f3 = *(const float4*)(ap + 12);
    const u16* bph = &WTh[(size_t)(n0 + row) * ldwt + k0 + half * 16];
    const u16* bpl = &WTl[(size_t)(n0 + row) * ldwt + k0 + half * 16];
    u16x8 bh0 = *(const u16x8*)(bph + 0);
    u16x8 bh1 = *(const u16x8*)(bph + 8);
    u16x8 bl0 = *(const u16x8*)(bpl + 0);
    u16x8 bl1 = *(const u16x8*)(bpl + 8);
    u16x8 ah0, ah1, al0, al1;
    float fa[8] = {f0.x, f0.y, f0.z, f0.w, f1.x, f1.y, f1.z, f1.w};
    float fb[8] = {f2.x, f2.y, f2.z, f2.w, f3.x, f3.y, f3.z, f3.w};
#pragma unroll
    for (int i = 0; i < 8; ++i) {
      unsigned int s0 = split2(fa[i]);
      unsigned int s1 = split2(fb[i]);
      ah0[i] = (u16)(s0 & 0xffffu); al0[i] = (u16)(s0 >> 16);
      ah1[i] = (u16)(s1 & 0xffffu); al1[i] = (u16)(s1 >> 16);
    }
    __syncthreads();
    *(u16x8*)&Ash[row * 40 + half * 16 + 0] = ah0;
    *(u16x8*)&Ash[row * 40 + half * 16 + 8] = ah1;
    *(u16x8*)&Asl[row * 40 + half * 16 + 0] = al0;
    *(u16x8*)&Asl[row * 40 + half * 16 + 8] = al1;
    *(u16x8*)&Bsh[row * 40 + half * 16 + 0] = bh0;
    *(u16x8*)&Bsh[row * 40 + half * 16 + 8] = bh1;
    *(u16x8*)&Bsl[row * 40 + half * 16 + 0] = bl0;
    *(u16x8*)&Bsl[row * 40 + half * 16 + 8] = bl1;
    __syncthreads();

    bf16x8 afh[4], afl[4], bfh[4], bfl[4];
#pragma unroll
    for (int mi = 0; mi < 4; ++mi) {
      afh[mi] = *(const bf16x8*)&Ash[(wm + mi * 16 + lm) * 40 + k8];
      afl[mi] = *(const bf16x8*)&Asl[(wm + mi * 16 + lm) * 40 + k8];
    }
#pragma unroll
    for (int ni = 0; ni < 4; ++ni) {
      bfh[ni] = *(const bf16x8*)&Bsh[(wn + ni * 16 + lm) * 40 + k8];
      bfl[ni] = *(const bf16x8*)&Bsl[(wn + ni * 16 + lm) * 40 + k8];
    }
#pragma unroll
    for (int mi = 0; mi < 4; ++mi)
#pragma unroll
      for (int ni = 0; ni < 4; ++ni) {
        acc[mi][ni] = __builtin_amdgcn_mfma_f32_16x16x32_bf16(afh[mi], bfh[ni], acc[mi][ni], 0, 0, 0);
        acc[mi][ni] = __builtin_amdgcn_mfma_f32_16x16x32_bf16(afh[mi], bfl[ni], acc[mi][ni], 0, 0, 0);
        acc[mi][ni] = __builtin_amdgcn_mfma_f32_16x16x32_bf16(afl[mi], bfh[ni], acc[mi][ni], 0, 0, 0);
      }
  }

#pragma unroll
  for (int mi = 0; mi < 4; ++mi) {
#pragma unroll
    for (int ni = 0; ni < 4; ++ni) {
      int gcol = n0 + wn + ni * 16 + lm;
#pragma unroll
      for (int r = 0; r < 4; ++r) {
        int grow = m0 + wm + mi * 16 + quad * 4 + r;
        float v = acc[mi][ni][r];
        size_t ci = (size_t)grow * ldc + gcol;
        if (mode == 3) {
          if (bias) v += bias[gcol];
          unsigned int s = split2(v);
          u16* ch = (u16*)C;
          ch[ci] = (u16)(s & 0xffffu);
          ch[ci + NBLD_] = (u16)(s >> 16);
        } else {
          if (mode == 1) {
            v = gelu_f(v);
          } else if (mode == 2) {
            v += C[ci];
          } else {
            if (bias) v += bias[gcol];
            if (R) v += R[ci];
          }
          C[ci] = v;
        }
      }
    }
  }
}

// ---------------- split-MFMA Q.K^T with diagonal (mod-L) reduction ----------------
// q,k are PRE-SPLIT u16 arrays: hi at [b][l][d], lo at +NBLD_. No in-kernel split.
// bins aliased onto Ash after the MFMA loop -> LDS exactly 40 KB (4 blocks/CU).
__global__ __launch_bounds__(256) void corr_mfma_k(
    const u16* __restrict__ q, const u16* __restrict__ kmat, float* __restrict__ mc)
{
  __shared__ u16 Ash[128 * 40];
  __shared__ u16 Asl[128 * 40];
  __shared__ u16 Bsh[128 * 40];
  __shared__ u16 Bsl[128 * 40];
  const int t = threadIdx.x;
  const int i0 = blockIdx.x * 128, j0 = blockIdx.y * 128, b = blockIdx.z;
  const int row = t >> 1, half = t & 1;
  const int lane = t & 63, wid = t >> 6;
  const int wm = (wid & 1) * 64, wn = (wid >> 1) * 64;
  const int lm = lane & 15, quad = lane >> 4, k8 = quad * 8;

  f32x4 acc[4][4];
#pragma unroll
  for (int i = 0; i < 4; ++i)
#pragma unroll
    for (int j = 0; j < 4; ++j) acc[i][j] = (f32x4){0.f, 0.f, 0.f, 0.f};

  for (int k0 = 0; k0 < D_; k0 += 32) {
    const u16* aph = &q[((size_t)b * L_ + i0 + row) * D_ + k0 + half * 16];
    const u16* bph = &kmat[((size_t)b * L_ + j0 + row) * D_ + k0 + half * 16];
    u16x8 ah0 = *(const u16x8*)(aph + 0);
    u16x8 ah1 = *(const u16x8*)(aph + 8);
    u16x8 al0 = *(const u16x8*)(aph + NBLD_ + 0);
    u16x8 al1 = *(const u16x8*)(aph + NBLD_ + 8);
    u16x8 bh0 = *(const u16x8*)(bph + 0);
    u16x8 bh1 = *(const u16x8*)(bph + 8);
    u16x8 bl0 = *(const u16x8*)(bph + NBLD_ + 0);
    u16x8 bl1 = *(const u16x8*)(bph + NBLD_ + 8);
    __syncthreads();
    *(u16x8*)&Ash[row * 40 + half * 16 + 0] = ah0;
    *(u16x8*)&Ash[row * 40 + half * 16 + 8] = ah1;
    *(u16x8*)&Asl[row * 40 + half * 16 + 0] = al0;
    *(u16x8*)&Asl[row * 40 + half * 16 + 8] = al1;
    *(u16x8*)&Bsh[row * 40 + half * 16 + 0] = bh0;
    *(u16x8*)&Bsh[row * 40 + half * 16 + 8] = bh1;
    *(u16x8*)&Bsl[row * 40 + half * 16 + 0] = bl0;
    *(u16x8*)&Bsl[row * 40 + half * 16 + 8] = bl1;
    __syncthreads();

    bf16x8 afh[4], afl[4], bfh[4], bfl[4];
#pragma unroll
    for (int mi = 0; mi < 4; ++mi) {
      afh[mi] = *(const bf16x8*)&Ash[(wm + mi * 16 + lm) * 40 + k8];
      afl[mi] = *(const bf16x8*)&Asl[(wm + mi * 16 + lm) * 40 + k8];
    }
#pragma unroll
    for (int ni = 0; ni < 4; ++ni) {
      bfh[ni] = *(const bf16x8*)&Bsh[(wn + ni * 16 + lm) * 40 + k8];
      bfl[ni] = *(const bf16x8*)&Bsl[(wn + ni * 16 + lm) * 40 + k8];
    }
#pragma unroll
    for (int mi = 0; mi < 4; ++mi)
#pragma unroll
      for (int ni = 0; ni < 4; ++ni) {
        acc[mi][ni] = __builtin_amdgcn_mfma_f32_16x16x32_bf16(afh[mi], bfh[ni], acc[mi][ni], 0, 0, 0);
        acc[mi][ni] = __builtin_amdgcn_mfma_f32_16x16x32_bf16(afh[mi], bfl[ni], acc[mi][ni], 0, 0, 0);
        acc[mi][ni] = __builtin_amdgcn_mfma_f32_16x16x32_bf16(afl[mi], bfh[ni], acc[mi][ni], 0, 0, 0);
      }
  }

  // epilogue: alias diag bins onto Ash (done with staging)
  __syncthreads();
  float* bins = (float*)Ash;
  if (t < 256) bins[t] = 0.f;
  __syncthreads();
#pragma unroll
  for (int mi = 0; mi < 4; ++mi)
#pragma unroll
    for (int ni = 0; ni < 4; ++ni) {
      int cj = wn + ni * 16 + lm;
#pragma unroll
      for (int r = 0; r < 4; ++r) {
        int ri = wm + mi * 16 + quad * 4 + r;
        atomicAdd(&bins[ri - cj + 127], acc[mi][ni][r]);
      }
    }
  __syncthreads();
  if (t < 255) {
    int tau = (i0 - j0 + t - 127 + 2 * L_) & (L_ - 1);
    atomicAdd(&mc[(size_t)b * L_ + tau], bins[t] * (1.0f / 512.0f));
  }
}

// ---------------- fp32 GEMM (final projection) ----------------
__global__ __launch_bounds__(256) void gemm_k(
    const float* __restrict__ A, int lda,
    const float* __restrict__ W, int ldw,
    float* __restrict__ C, int ldc,
    const float* __restrict__ bias,
    const float* __restrict__ R,
    int K, int mode)
{
  __shared__ float As[TBK][TM + 4];
  __shared__ float Bs[TBK][TN + 4];
  const int t = threadIdx.x;
  const int m0 = blockIdx.x * TM;
  const int n0 = blockIdx.y * TN;
  const int tx = t & 15, ty = t >> 4;
  const int ar = t >> 2, akv = (t & 3) * 4;
  const int bkk = t >> 4, bc = (t & 15) * 4;
  float acc[4][4] = {};
  for (int k0 = 0; k0 < K; k0 += TBK) {
    float4 a4 = *(const float4*)&A[(size_t)(m0 + ar) * lda + (k0 + akv)];
    float4 w4 = *(const float4*)&W[(size_t)(k0 + bkk) * ldw + (n0 + bc)];
    __syncthreads();
    As[akv + 0][ar] = a4.x; As[akv + 1][ar] = a4.y;
    As[akv + 2][ar] = a4.z; As[akv + 3][ar] = a4.w;
    *(float4*)&Bs[bkk][bc] = w4;
    __syncthreads();
#pragma unroll
    for (int kk = 0; kk < TBK; ++kk) {
      float4 a = *(const float4*)&As[kk][ty * 4];
      float4 b = *(const float4*)&Bs[kk][tx * 4];
      float av[4] = {a.x, a.y, a.z, a.w};
      float bv[4] = {b.x, b.y, b.z, b.w};
#pragma unroll
      for (int i = 0; i < 4; ++i)
#pragma unroll
        for (int j = 0; j < 4; ++j) acc[i][j] += av[i] * bv[j];
    }
  }
#pragma unroll
  for (int i = 0; i < 4; ++i) {
    int m = m0 + ty * 4 + i;
    float* crow = &C[(size_t)m * ldc + (n0 + tx * 4)];
    float4 v = make_float4(acc[i][0], acc[i][1], acc[i][2], acc[i][3]);
    if (mode == 1) {
      v.x = gelu_f(v.x); v.y = gelu_f(v.y); v.z = gelu_f(v.z); v.w = gelu_f(v.w);
    } else if (mode == 2) {
      float4 o = *(const float4*)crow;
      v.x += o.x; v.y += o.y; v.z += o.z; v.w += o.w;
    } else {
      if (bias) {
        const float* bp = &bias[n0 + tx * 4];
        v.x += bp[0]; v.y += bp[1]; v.z += bp[2]; v.w += bp[3];
      }
      if (R) {
        float4 rv = *(const float4*)&R[(size_t)m * ldc + (n0 + tx * 4)];
        v.x += rv.x; v.y += rv.y; v.z += rv.z; v.w += rv.w;
      }
    }
    *(float4*)crow = v;
  }
}

// ---------------- embedding: circular conv1d(k=3) as gathered GEMM ----------------
__global__ __launch_bounds__(256) void embed_k(
    const float* __restrict__ x, const float* __restrict__ W, float* __restrict__ C)
{
  __shared__ float As[TBK][TM + 4];
  __shared__ float Bs[TBK][TN + 4];
  const int t = threadIdx.x;
  const int m0 = blockIdx.x * TM, n0 = blockIdx.y * TN;
  const int tx = t & 15, ty = t >> 4;
  const int ar = t >> 2, akv = (t & 3) * 4;
  const int bkk = t >> 4, bc = (t & 15) * 4;
  const int m = m0 + ar, mb = m >> 10, ml = m & (L_ - 1);
  float acc[4][4] = {};
  for (int k0 = 0; k0 < 3 * CIN_; k0 += TBK) {
    int kcol = k0 + akv;
    int j = kcol >> 6, c = kcol & 63;
    int lsrc = (ml + j - 1 + L_) & (L_ - 1);
    float4 a4 = *(const float4*)&x[((size_t)mb * L_ + lsrc) * CIN_ + c];
    float4 w4 = *(const float4*)&W[(size_t)(k0 + bkk) * D_ + (n0 + bc)];
    __syncthreads();
    As[akv + 0][ar] = a4.x; As[akv + 1][ar] = a4.y;
    As[akv + 2][ar] = a4.z; As[akv + 3][ar] = a4.w;
    *(float4*)&Bs[bkk][bc] = w4;
    __syncthreads();
#pragma unroll
    for (int kk = 0; kk < TBK; ++kk) {
      float4 a = *(const float4*)&As[kk][ty * 4];
      float4 b = *(const float4*)&Bs[kk][tx * 4];
      float av[4] = {a.x, a.y, a.z, a.w};
      float bv[4] = {b.x, b.y, b.z, b.w};
#pragma unroll
      for (int i = 0; i < 4; ++i)
#pragma unroll
        for (int jj = 0; jj < 4; ++jj) acc[i][jj] += av[i] * bv[jj];
    }
  }
#pragma unroll
  for (int i = 0; i < 4; ++i) {
    int mm = m0 + ty * 4 + i;
    *(float4*)&C[(size_t)mm * D_ + (n0 + tx * 4)] =
        make_float4(acc[i][0], acc[i][1], acc[i][2], acc[i][3]);
  }
}

// ---------------- top-6 + softmax ----------------
__global__ __launch_bounds__(256) void topk_k(const float* __restrict__ mc,
                                              float* __restrict__ tc, int* __restrict__ dly)
{
  const int b = blockIdx.x, t = threadIdx.x;
  __shared__ float vals[L_];
  __shared__ float rv[256];
  __shared__ int ri[256];
  __shared__ float wsel[TOPK_];
  __shared__ int dsel[TOPK_];
  for (int i = t; i < L_; i += 256) vals[i] = mc[(size_t)b * L_ + i];
  __syncthreads();
  for (int kk = 0; kk < TOPK_; ++kk) {
    float bv = -INFINITY; int bi = 0x7fffffff;
    for (int i = t; i < L_; i += 256) {
      float v = vals[i];
      if (v > bv) { bv = v; bi = i; }
    }
    rv[t] = bv; ri[t] = bi;
    __syncthreads();
    for (int s = 128; s > 0; s >>= 1) {
      if (t < s) {
        if (rv[t + s] > rv[t] || (rv[t + s] == rv[t] && ri[t + s] < ri[t])) {
          rv[t] = rv[t + s]; ri[t] = ri[t + s];
        }
      }
      __syncthreads();
    }
    if (t == 0) { wsel[kk] = rv[0]; dsel[kk] = ri[0]; vals[ri[0]] = -INFINITY; }
    __syncthreads();
  }
  if (t == 0) {
    float m = wsel[0];
    float e[TOPK_], se = 0.f;
    for (int k = 0; k < TOPK_; ++k) { e[k] = expf(wsel[k] - m); se += e[k]; }
    for (int k = 0; k < TOPK_; ++k) {
      tc[b * TOPK_ + k] = e[k] / se;
      dly[b * TOPK_ + k] = dsel[k];
    }
  }
}

// ---------------- weighted delay-gather ----------------
__global__ __launch_bounds__(256) void gather_k(const float* __restrict__ v,
    const float* __restrict__ tc, const int* __restrict__ dly, float* __restrict__ out)
{
  int tid = blockIdx.x * 256 + threadIdx.x;
  int c4 = tid & 127;
  int row = tid >> 7;
  int b = row >> 10, l = row & (L_ - 1);
  const float4* vb = (const float4*)(v + (size_t)b * L_ * D_);
  float4 o = make_float4(0.f, 0.f, 0.f, 0.f);
#pragma unroll
  for (int k = 0; k < TOPK_; ++k) {
    int ld = (l + dly[b * TOPK_ + k]) & (L_ - 1);
    float w = tc[b * TOPK_ + k];
    float4 vv = vb[(size_t)ld * (D_ / 4) + c4];
    o.x += w * vv.x; o.y += w * vv.y; o.z += w * vv.z; o.w += w * vv.w;
  }
  ((float4*)out)[tid] = o;
}

// ---------------- series decomposition ----------------
__global__ __launch_bounds__(256) void decomp_k(const float* __restrict__ s,
                                                float* __restrict__ out)
{
  __shared__ float tile[152][64];
  const int t = threadIdx.x;
  const int l0 = blockIdx.x * 128, d0 = blockIdx.y * 64, b = blockIdx.z;
  const float* sb = s + (size_t)b * L_ * D_;
  for (int idx = t; idx < 152 * 16; idx += 256) {
    int row = idx >> 4, c4 = (idx & 15) * 4;
    int lsrc = l0 - 12 + row;
    lsrc = lsrc < 0 ? 0 : (lsrc > L_ - 1 ? L_ - 1 : lsrc);
    *(float4*)&tile[row][c4] = *(const float4*)&sb[(size_t)lsrc * D_ + d0 + c4];
  }
  __syncthreads();
  const int d = t & 63, lb = t >> 6;
  float* ob = out + (size_t)b * L_ * D_;
  for (int it = 0; it < 32; ++it) {
    int lp = lb + it * 4;
    float sum = 0.f;
#pragma unroll
    for (int j = 0; j < 25; ++j) sum += tile[lp + j][d];
    ob[(size_t)(l0 + lp) * D_ + d0 + d] = tile[lp + 12][d] - sum * (1.0f / 25.0f);
  }
}

// ---------------- LayerNorm over D ----------------
__global__ __launch_bounds__(256) void ln_k(const float* __restrict__ a,
    const float* __restrict__ g, const float* __restrict__ be, float* __restrict__ out)
{
  __shared__ float red[256];
  const int row = blockIdx.x, t = threadIdx.x;
  const float* p = a + (size_t)row * D_;
  float x0 = p[t], x1 = p[t + 256];
  red[t] = x0 + x1;
  __syncthreads();
  for (int s = 128; s > 0; s >>= 1) { if (t < s) red[t] += red[t + s]; __syncthreads(); }
  float mu = red[0] * (1.0f / 512.0f);
  __syncthreads();
  float d0 = x0 - mu, d1 = x1 - mu;
  red[t] = d0 * d0 + d1 * d1;
  __syncthreads();
  for (int s = 128; s > 0; s >>= 1) { if (t < s) red[t] += red[t + s]; __syncthreads(); }
  float rs = rsqrtf(red[0] * (1.0f / 512.0f) + 1e-5f);
  out[(size_t)row * D_ + t]       = d0 * rs * g[t] + be[t];
  out[(size_t)row * D_ + t + 256] = d1 * rs * g[t + 256] + be[t + 256];
}

// ---------------- subtract per-(b,d) time mean over L ----------------
__global__ __launch_bounds__(256) void colmean_k(const float* __restrict__ a,
                                                 float* __restrict__ out)
{
  int tid = blockIdx.x * 256 + threadIdx.x;
  int b = tid >> 9, d = tid & (D_ - 1);
  const float* p = a + (size_t)b * L_ * D_ + d;
  float sum = 0.f;
  for (int l = 0; l < L_; ++l) sum += p[(size_t)l * D_];
  float mu = sum * (1.0f / 1024.0f);
  float* q = out + (size_t)b * L_ * D_ + d;
  for (int l = 0; l < L_; ++l) q[(size_t)l * D_] = p[(size_t)l * D_] - mu;
}

extern "C" void kernel_launch(void* const* d_in, const int* in_sizes, int n_in,
                              void* d_out, int out_size, void* d_ws, size_t ws_size,
                              hipStream_t stream) {
  (void)n_in; (void)in_sizes; (void)ws_size; (void)out_size;
  const float* x    = (const float*)d_in[0];
  const float* embw = (const float*)d_in[1];
  const float* wq   = (const float*)d_in[2];
  const float* bq   = (const float*)d_in[3];
  const float* wk   = (const float*)d_in[4];
  const float* bk   = (const float*)d_in[5];
  const float* wv   = (const float*)d_in[6];
  const float* bv   = (const float*)d_in[7];
  const float* wo   = (const float*)d_in[8];
  const float* bo   = (const float*)d_in[9];
  const float* w1   = (const float*)d_in[10];
  const float* w2   = (const float*)d_in[11];
  const float* lng  = (const float*)d_in[12];
  const float* lnb  = (const float*)d_in[13];
  const float* pw   = (const float*)d_in[14];
  const float* pb   = (const float*)d_in[15];

  const size_t nBLD = NBLD_;
  float* h  = (float*)d_ws;
  float* t0 = h + nBLD;           // also holds split Q (u16 hi + lo)
  float* t1 = t0 + nBLD;          // also holds split K
  float* mcorr = t1 + nBLD;
  float* tc    = mcorr + (size_t)B_ * L_;
  int*   dly   = (int*)(tc + B_ * TOPK_);
  // split bf16 transposed weights (hi/lo)
  u16* base = (u16*)(dly + B_ * TOPK_ + 64);
  const size_t nDD = (size_t)NL_ * D_ * D_, nDF = (size_t)NL_ * D_ * DFF_;
  u16* wqTh = base;             u16* wqTl = wqTh + nDD;
  u16* wkTh = wqTl + nDD;       u16* wkTl = wkTh + nDD;
  u16* wvTh = wkTl + nDD;       u16* wvTl = wvTh + nDD;
  u16* woTh = wvTl + nDD;       u16* woTl = woTh + nDD;
  u16* w1Th = woTl + nDD;       u16* w1Tl = w1Th + nDF;
  u16* w2Th = w1Tl + nDF;       u16* w2Tl = w2Th + nDF;

  dim3 blk(256);
  const dim3 gGemm(512, 8);        // fp32 64x64 tiles (embed only)
  const dim3 gMfma(256, 4);        // 128x128 tiles, N=512
  const dim3 gCorr(8, 8, B_);      // 128x128 QK^T tiles

  for (int l = 0; l < NL_; ++l) {
    transp_split_k<<<dim3(16, 16), blk, 0, stream>>>(wq + (size_t)l * D_ * D_,
        wqTh + (size_t)l * D_ * D_, wqTl + (size_t)l * D_ * D_, D_, D_);
    transp_split_k<<<dim3(16, 16), blk, 0, stream>>>(wk + (size_t)l * D_ * D_,
        wkTh + (size_t)l * D_ * D_, wkTl + (size_t)l * D_ * D_, D_, D_);
    transp_split_k<<<dim3(16, 16), blk, 0, stream>>>(wv + (size_t)l * D_ * D_,
        wvTh + (size_t)l * D_ * D_, wvTl + (size_t)l * D_ * D_, D_, D_);
    transp_split_k<<<dim3(16, 16), blk, 0, stream>>>(wo + (size_t)l * D_ * D_,
        woTh + (size_t)l * D_ * D_, woTl + (size_t)l * D_ * D_, D_, D_);
    transp_split_k<<<dim3(16, 64), blk, 0, stream>>>(w1 + (size_t)l * D_ * DFF_,
        w1Th + (size_t)l * D_ * DFF_, w1Tl + (size_t)l * D_ * DFF_, D_, DFF_);
    transp_split_k<<<dim3(64, 16), blk, 0, stream>>>(w2 + (size_t)l * DFF_ * D_,
        w2Th + (size_t)l * DFF_ * D_, w2Tl + (size_t)l * DFF_ * D_, DFF_, D_);
  }

  embed_k<<<gGemm, blk, 0, stream>>>(x, embw, h);

  for (int l = 0; l < NL_; ++l) {
    const bool last = (l == NL_ - 1);   // post-selection layer: plain bf16 is safe
    const size_t oDD = (size_t)l * D_ * D_;

    // Q -> t0 (split u16), K -> t1 (split u16)
    mfma_split_gemm_k<<<gMfma, blk, 0, stream>>>(h, D_, wqTh + oDD, wqTl + oDD, D_, t0, D_, bq + (size_t)l * D_, nullptr, D_, 3);
    mfma_split_gemm_k<<<gMfma, blk, 0, stream>>>(h, D_, wkTh + oDD, wkTl + oDD, D_, t1, D_, bk + (size_t)l * D_, nullptr, D_, 3);

    zero_k<<<dim3(128), blk, 0, stream>>>(mcorr, B_ * L_);
    corr_mfma_k<<<gCorr, blk, 0, stream>>>((const u16*)t0, (const u16*)t1, mcorr);
    topk_k<<<dim3(B_), blk, 0, stream>>>(mcorr, tc, dly);

    // V -> t0 (fp32, overwrites Q), gather -> t1
    if (last)
      mfma_gemm_k<<<gMfma, blk, 0, stream>>>(h, D_, wvTh + oDD, D_, t0, D_, bv + (size_t)l * D_, nullptr, D_, 0);
    else
      mfma_split_gemm_k<<<gMfma, blk, 0, stream>>>(h, D_, wvTh + oDD, wvTl + oDD, D_, t0, D_, bv + (size_t)l * D_, nullptr, D_, 0);
    gather_k<<<dim3(16384), blk, 0, stream>>>(t0, tc, dly, t1);

    // out proj + bias + residual(h) -> t0 ; decomp -> h
    if (last)
      mfma_gemm_k<<<gMfma, blk, 0, stream>>>(t1, D_, woTh + oDD, D_, t0, D_, bo + (size_t)l * D_, h, D_, 0);
    else
      mfma_split_gemm_k<<<gMfma, blk, 0, stream>>>(t1, D_, woTh + oDD, woTl + oDD, D_, t0, D_, bo + (size_t)l * D_, h, D_, 0);
    decomp_k<<<dim3(8, 8, B_), blk, 0, stream>>>(t0, h);

    // FFN: 4 chunks of DFF=512; u -> t1 (gelu), accumulate into t0 (chunk0 carries +h)
    for (int c = 0; c < 4; ++c) {
      const u16* w1ch = w1Th + (size_t)l * D_ * DFF_ + (size_t)c * 512 * D_;
      const u16* w1cl = w1Tl + (size_t)l * D_ * DFF_ + (size_t)c * 512 * D_;
      const u16* w2ch = w2Th + (size_t)l * DFF_ * D_ + (size_t)c * 512;
      const u16* w2cl = w2Tl + (size_t)l * DFF_ * D_ + (size_t)c * 512;
      if (last) {
        mfma_gemm_k<<<gMfma, blk, 0, stream>>>(h, D_, w1ch, D_, t1, D_, nullptr, nullptr, D_, 1);
        if (c == 0)
          mfma_gemm_k<<<gMfma, blk, 0, stream>>>(t1, D_, w2ch, DFF_, t0, D_, nullptr, h, D_, 0);
        else
          mfma_gemm_k<<<gMfma, blk, 0, stream>>>(t1, D_, w2ch, DFF_, t0, D_, nullptr, nullptr, D_, 2);
      } else {
        mfma_split_gemm_k<<<gMfma, blk, 0, stream>>>(h, D_, w1ch, w1cl, D_, t1, D_, nullptr, nullptr, D_, 1);
        if (c == 0)
          mfma_split_gemm_k<<<gMfma, blk, 0, stream>>>(t1, D_, w2ch, w2cl, DFF_, t0, D_, nullptr, h, D_, 0);
        else
          mfma_split_gemm_k<<<gMfma, blk, 0, stream>>>(t1, D_, w2ch, w2cl, DFF_, t0, D_, nullptr, nullptr, D_, 2);
      }
    }
    decomp_k<<<dim3(8, 8, B_), blk, 0, stream>>>(t0, h);
  }

  ln_k<<<dim3(B_ * L_), blk, 0, stream>>>(h, lng, lnb, t0);
  colmean_k<<<dim3((B_ * D_) / 256), blk, 0, stream>>>(t0, t1);
  gemm_k<<<dim3(512, 1), blk, 0, stream>>>(t1, D_, pw, CIN_, (float*)d_out, CIN_, pb, nullptr, D_, 0);
}

// Round 12
// 4454.898 us; speedup vs baseline: 1.0864x; 1.0864x over previous
//
#include <hip/hip_runtime.h>
#include <hip/hip_bf16.h>
#include <math.h>

#define B_   32
#define L_   1024
#define CIN_ 64
#define D_   512
#define DFF_ 2048
#define NL_  3
#define TOPK_ 6
#define NBLD_ ((size_t)B_ * L_ * D_)

#define TM 64
#define TN 64
#define TBK 16

typedef unsigned short u16;
typedef __bf16 bf16x8 __attribute__((ext_vector_type(8)));
typedef float  f32x4  __attribute__((ext_vector_type(4)));

typedef const __attribute__((address_space(1))) void* gp1_t;
typedef __attribute__((address_space(3))) void* lp3_t;

__device__ __forceinline__ void gll16(const void* g, void* l) {
  __builtin_amdgcn_global_load_lds((gp1_t)g, (lp3_t)l, 16, 0, 0);
}

__device__ __forceinline__ float bf2f(u16 u) {
  return __uint_as_float(((unsigned int)u) << 16);
}
__device__ __forceinline__ u16 f2bf(float f) {
  unsigned int u = __float_as_uint(f);
  return (u16)((u + 0x7fffu + ((u >> 16) & 1u)) >> 16);   // RNE
}
// packed split: lo16 of word = bf16(f) [hi part], hi16 of word = bf16(residual)
__device__ __forceinline__ unsigned int split2(float f) {
  u16 hi = f2bf(f);
  u16 lo = f2bf(f - bf2f(hi));
  return (unsigned int)hi | ((unsigned int)lo << 16);
}
__device__ __forceinline__ float gelu_f(float x) {
  return 0.5f * x * (1.0f + erff(x * 0.70710678118654752440f));
}

__global__ __launch_bounds__(256) void zero_k(float* __restrict__ p, int n) {
  int i = blockIdx.x * 256 + threadIdx.x;
  if (i < n) p[i] = 0.f;
}

// ---------------- weight transpose + bf16x2 split ----------------
__global__ __launch_bounds__(256) void transp_split_k(const float* __restrict__ W,
                                                      u16* __restrict__ WTh,
                                                      u16* __restrict__ WTl, int K, int N) {
  __shared__ float tile[32][33];
  const int t = threadIdx.x;
  const int k0 = blockIdx.x * 32, n0 = blockIdx.y * 32;
  const int tx = t & 31, ty = t >> 5;
#pragma unroll
  for (int i = 0; i < 4; ++i) {
    int kk = ty + i * 8;
    tile[kk][tx] = W[(size_t)(k0 + kk) * N + n0 + tx];
  }
  __syncthreads();
#pragma unroll
  for (int i = 0; i < 4; ++i) {
    int nn = ty + i * 8;
    unsigned int s = split2(tile[tx][nn]);
    WTh[(size_t)(n0 + nn) * K + k0 + tx] = (u16)(s & 0xffffu);
    WTl[(size_t)(n0 + nn) * K + k0 + tx] = (u16)(s >> 16);
  }
}

// ============ async split MFMA GEMM: C = op(A(hi+lo) @ W(hi+lo)^T) ============
// A pre-split u16 planes (Al = lo plane ptr), W pre-split. 128x128 tile, BK=32.
// LDS unpadded 128x32 u16 per array with XOR quarter-swizzle; global_load_lds.
// mode 0: +bias +R(hi/lo) -> fp32 C ; 1: gelu -> split C ; 2: fp32 C += ; 3: +bias -> split C
__global__ __launch_bounds__(256) void mfma_split_gemm_k(
    const u16* __restrict__ Ah, const u16* __restrict__ Al, int lda,
    const u16* __restrict__ Wh, const u16* __restrict__ Wl, int ldwt,
    void* __restrict__ Cv, int ldc,
    const float* __restrict__ bias,
    const u16* __restrict__ Rh, const u16* __restrict__ Rl,
    int K, int mode)
{
  __shared__ u16 Ash[128 * 32];
  __shared__ u16 Asl[128 * 32];
  __shared__ u16 Bsh[128 * 32];
  __shared__ u16 Bsl[128 * 32];
  const int t = threadIdx.x;
  const int m0 = blockIdx.x * 128, n0 = blockIdx.y * 128;
  const int lane = t & 63, w = t >> 6;
  const int lrow = lane >> 2, lq = lane & 3;
  const int qg8 = (lq ^ ((lrow >> 1) & 3)) * 8;          // swizzled global quarter
  const int wm = (w & 1) * 64, wn = (w >> 1) * 64;
  const int lm = lane & 15, quad = lane >> 4;
  const int kq8 = (quad ^ ((lm >> 1) & 3)) * 8;          // swizzled LDS quarter

  f32x4 acc[4][4];
#pragma unroll
  for (int i = 0; i < 4; ++i)
#pragma unroll
    for (int j = 0; j < 4; ++j) acc[i][j] = (f32x4){0.f, 0.f, 0.f, 0.f};

  for (int k0 = 0; k0 < K; k0 += 32) {
    __syncthreads();
#pragma unroll
    for (int seg = 0; seg < 2; ++seg) {
      const int r0 = w * 32 + seg * 16;
      const size_t ga = (size_t)(m0 + r0 + lrow) * lda + k0 + qg8;
      const size_t gb = (size_t)(n0 + r0 + lrow) * ldwt + k0 + qg8;
      gll16(Ah + ga, &Ash[r0 * 32]);
      gll16(Al + ga, &Asl[r0 * 32]);
      gll16(Wh + gb, &Bsh[r0 * 32]);
      gll16(Wl + gb, &Bsl[r0 * 32]);
    }
    __syncthreads();

    bf16x8 afh[4], afl[4], bfh[4], bfl[4];
#pragma unroll
    for (int mi = 0; mi < 4; ++mi) {
      afh[mi] = *(const bf16x8*)&Ash[(wm + mi * 16 + lm) * 32 + kq8];
      afl[mi] = *(const bf16x8*)&Asl[(wm + mi * 16 + lm) * 32 + kq8];
    }
#pragma unroll
    for (int ni = 0; ni < 4; ++ni) {
      bfh[ni] = *(const bf16x8*)&Bsh[(wn + ni * 16 + lm) * 32 + kq8];
      bfl[ni] = *(const bf16x8*)&Bsl[(wn + ni * 16 + lm) * 32 + kq8];
    }
#pragma unroll
    for (int mi = 0; mi < 4; ++mi)
#pragma unroll
      for (int ni = 0; ni < 4; ++ni) {
        acc[mi][ni] = __builtin_amdgcn_mfma_f32_16x16x32_bf16(afh[mi], bfh[ni], acc[mi][ni], 0, 0, 0);
        acc[mi][ni] = __builtin_amdgcn_mfma_f32_16x16x32_bf16(afh[mi], bfl[ni], acc[mi][ni], 0, 0, 0);
        acc[mi][ni] = __builtin_amdgcn_mfma_f32_16x16x32_bf16(afl[mi], bfh[ni], acc[mi][ni], 0, 0, 0);
      }
  }

  float* Cf = (float*)Cv;
  u16* Cu = (u16*)Cv;
#pragma unroll
  for (int mi = 0; mi < 4; ++mi) {
#pragma unroll
    for (int ni = 0; ni < 4; ++ni) {
      int gcol = n0 + wn + ni * 16 + lm;
#pragma unroll
      for (int r = 0; r < 4; ++r) {
        int grow = m0 + wm + mi * 16 + quad * 4 + r;
        float v = acc[mi][ni][r];
        size_t ci = (size_t)grow * ldc + gcol;
        if (mode == 0) {
          if (bias) v += bias[gcol];
          if (Rh) v += bf2f(Rh[ci]) + bf2f(Rl[ci]);
          Cf[ci] = v;
        } else if (mode == 1) {
          unsigned int s = split2(gelu_f(v));
          Cu[ci] = (u16)(s & 0xffffu);
          Cu[ci + NBLD_] = (u16)(s >> 16);
        } else if (mode == 2) {
          Cf[ci] = v + Cf[ci];
        } else {
          if (bias) v += bias[gcol];
          unsigned int s = split2(v);
          Cu[ci] = (u16)(s & 0xffffu);
          Cu[ci + NBLD_] = (u16)(s >> 16);
        }
      }
    }
  }
}

// ============ async plain bf16 MFMA GEMM (hi planes only, last layer) ============
__global__ __launch_bounds__(256) void mfma_plain_gemm_k(
    const u16* __restrict__ Ah, int lda,
    const u16* __restrict__ Wh, int ldwt,
    void* __restrict__ Cv, int ldc,
    const float* __restrict__ bias,
    const u16* __restrict__ Rh, const u16* __restrict__ Rl,
    int K, int mode)
{
  __shared__ u16 Ash[128 * 32];
  __shared__ u16 Bsh[128 * 32];
  const int t = threadIdx.x;
  const int m0 = blockIdx.x * 128, n0 = blockIdx.y * 128;
  const int lane = t & 63, w = t >> 6;
  const int lrow = lane >> 2, lq = lane & 3;
  const int qg8 = (lq ^ ((lrow >> 1) & 3)) * 8;
  const int wm = (w & 1) * 64, wn = (w >> 1) * 64;
  const int lm = lane & 15, quad = lane >> 4;
  const int kq8 = (quad ^ ((lm >> 1) & 3)) * 8;

  f32x4 acc[4][4];
#pragma unroll
  for (int i = 0; i < 4; ++i)
#pragma unroll
    for (int j = 0; j < 4; ++j) acc[i][j] = (f32x4){0.f, 0.f, 0.f, 0.f};

  for (int k0 = 0; k0 < K; k0 += 32) {
    __syncthreads();
#pragma unroll
    for (int seg = 0; seg < 2; ++seg) {
      const int r0 = w * 32 + seg * 16;
      const size_t ga = (size_t)(m0 + r0 + lrow) * lda + k0 + qg8;
      const size_t gb = (size_t)(n0 + r0 + lrow) * ldwt + k0 + qg8;
      gll16(Ah + ga, &Ash[r0 * 32]);
      gll16(Wh + gb, &Bsh[r0 * 32]);
    }
    __syncthreads();

    bf16x8 af[4], bf[4];
#pragma unroll
    for (int mi = 0; mi < 4; ++mi)
      af[mi] = *(const bf16x8*)&Ash[(wm + mi * 16 + lm) * 32 + kq8];
#pragma unroll
    for (int ni = 0; ni < 4; ++ni)
      bf[ni] = *(const bf16x8*)&Bsh[(wn + ni * 16 + lm) * 32 + kq8];
#pragma unroll
    for (int mi = 0; mi < 4; ++mi)
#pragma unroll
      for (int ni = 0; ni < 4; ++ni)
        acc[mi][ni] = __builtin_amdgcn_mfma_f32_16x16x32_bf16(af[mi], bf[ni], acc[mi][ni], 0, 0, 0);
  }

  float* Cf = (float*)Cv;
  u16* Cu = (u16*)Cv;
#pragma unroll
  for (int mi = 0; mi < 4; ++mi) {
#pragma unroll
    for (int ni = 0; ni < 4; ++ni) {
      int gcol = n0 + wn + ni * 16 + lm;
#pragma unroll
      for (int r = 0; r < 4; ++r) {
        int grow = m0 + wm + mi * 16 + quad * 4 + r;
        float v = acc[mi][ni][r];
        size_t ci = (size_t)grow * ldc + gcol;
        if (mode == 0) {
          if (bias) v += bias[gcol];
          if (Rh) v += bf2f(Rh[ci]) + bf2f(Rl[ci]);
          Cf[ci] = v;
        } else if (mode == 1) {
          unsigned int s = split2(gelu_f(v));
          Cu[ci] = (u16)(s & 0xffffu);
          Cu[ci + NBLD_] = (u16)(s >> 16);
        } else if (mode == 2) {
          Cf[ci] = v + Cf[ci];
        } else {
          if (bias) v += bias[gcol];
          unsigned int s = split2(v);
          Cu[ci] = (u16)(s & 0xffffu);
          Cu[ci + NBLD_] = (u16)(s >> 16);
        }
      }
    }
  }
}

// ============ async split-MFMA Q.K^T with diagonal (mod-L) reduction ============
// q,k pre-split u16 planes (lo at +NBLD_). bins aliased onto Ash.
__global__ __launch_bounds__(256) void corr_mfma_k(
    const u16* __restrict__ q, const u16* __restrict__ kmat, float* __restrict__ mc)
{
  __shared__ u16 Ash[128 * 32];
  __shared__ u16 Asl[128 * 32];
  __shared__ u16 Bsh[128 * 32];
  __shared__ u16 Bsl[128 * 32];
  const int t = threadIdx.x;
  const int i0 = blockIdx.x * 128, j0 = blockIdx.y * 128, b = blockIdx.z;
  const int lane = t & 63, w = t >> 6;
  const int lrow = lane >> 2, lq = lane & 3;
  const int qg8 = (lq ^ ((lrow >> 1) & 3)) * 8;
  const int wm = (w & 1) * 64, wn = (w >> 1) * 64;
  const int lm = lane & 15, quad = lane >> 4;
  const int kq8 = (quad ^ ((lm >> 1) & 3)) * 8;

  f32x4 acc[4][4];
#pragma unroll
  for (int i = 0; i < 4; ++i)
#pragma unroll
    for (int j = 0; j < 4; ++j) acc[i][j] = (f32x4){0.f, 0.f, 0.f, 0.f};

  for (int k0 = 0; k0 < D_; k0 += 32) {
    __syncthreads();
#pragma unroll
    for (int seg = 0; seg < 2; ++seg) {
      const int r0 = w * 32 + seg * 16;
      const size_t ga = ((size_t)b * L_ + i0 + r0 + lrow) * D_ + k0 + qg8;
      const size_t gb = ((size_t)b * L_ + j0 + r0 + lrow) * D_ + k0 + qg8;
      gll16(q + ga, &Ash[r0 * 32]);
      gll16(q + ga + NBLD_, &Asl[r0 * 32]);
      gll16(kmat + gb, &Bsh[r0 * 32]);
      gll16(kmat + gb + NBLD_, &Bsl[r0 * 32]);
    }
    __syncthreads();

    bf16x8 afh[4], afl[4], bfh[4], bfl[4];
#pragma unroll
    for (int mi = 0; mi < 4; ++mi) {
      afh[mi] = *(const bf16x8*)&Ash[(wm + mi * 16 + lm) * 32 + kq8];
      afl[mi] = *(const bf16x8*)&Asl[(wm + mi * 16 + lm) * 32 + kq8];
    }
#pragma unroll
    for (int ni = 0; ni < 4; ++ni) {
      bfh[ni] = *(const bf16x8*)&Bsh[(wn + ni * 16 + lm) * 32 + kq8];
      bfl[ni] = *(const bf16x8*)&Bsl[(wn + ni * 16 + lm) * 32 + kq8];
    }
#pragma unroll
    for (int mi = 0; mi < 4; ++mi)
#pragma unroll
      for (int ni = 0; ni < 4; ++ni) {
        acc[mi][ni] = __builtin_amdgcn_mfma_f32_16x16x32_bf16(afh[mi], bfh[ni], acc[mi][ni], 0, 0, 0);
        acc[mi][ni] = __builtin_amdgcn_mfma_f32_16x16x32_bf16(afh[mi], bfl[ni], acc[mi][ni], 0, 0, 0);
        acc[mi][ni] = __builtin_amdgcn_mfma_f32_16x16x32_bf16(afl[mi], bfh[ni], acc[mi][ni], 0, 0, 0);
      }
  }

  __syncthreads();
  float* bins = (float*)Ash;
  if (t < 256) bins[t] = 0.f;
  __syncthreads();
#pragma unroll
  for (int mi = 0; mi < 4; ++mi)
#pragma unroll
    for (int ni = 0; ni < 4; ++ni) {
      int cj = wn + ni * 16 + lm;
#pragma unroll
      for (int r = 0; r < 4; ++r) {
        int ri = wm + mi * 16 + quad * 4 + r;
        atomicAdd(&bins[ri - cj + 127], acc[mi][ni][r]);
      }
    }
  __syncthreads();
  if (t < 255) {
    int tau = (i0 - j0 + t - 127 + 2 * L_) & (L_ - 1);
    atomicAdd(&mc[(size_t)b * L_ + tau], bins[t] * (1.0f / 512.0f));
  }
}

// ---------------- fp32 GEMM (final projection) ----------------
__global__ __launch_bounds__(256) void gemm_k(
    const float* __restrict__ A, int lda,
    const float* __restrict__ W, int ldw,
    float* __restrict__ C, int ldc,
    const float* __restrict__ bias,
    int K)
{
  __shared__ float As[TBK][TM + 4];
  __shared__ float Bs[TBK][TN + 4];
  const int t = threadIdx.x;
  const int m0 = blockIdx.x * TM;
  const int n0 = blockIdx.y * TN;
  const int tx = t & 15, ty = t >> 4;
  const int ar = t >> 2, akv = (t & 3) * 4;
  const int bkk = t >> 4, bc = (t & 15) * 4;
  float acc[4][4] = {};
  for (int k0 = 0; k0 < K; k0 += TBK) {
    float4 a4 = *(const float4*)&A[(size_t)(m0 + ar) * lda + (k0 + akv)];
    float4 w4 = *(const float4*)&W[(size_t)(k0 + bkk) * ldw + (n0 + bc)];
    __syncthreads();
    As[akv + 0][ar] = a4.x; As[akv + 1][ar] = a4.y;
    As[akv + 2][ar] = a4.z; As[akv + 3][ar] = a4.w;
    *(float4*)&Bs[bkk][bc] = w4;
    __syncthreads();
#pragma unroll
    for (int kk = 0; kk < TBK; ++kk) {
      float4 a = *(const float4*)&As[kk][ty * 4];
      float4 b = *(const float4*)&Bs[kk][tx * 4];
      float av[4] = {a.x, a.y, a.z, a.w};
      float bv[4] = {b.x, b.y, b.z, b.w};
#pragma unroll
      for (int i = 0; i < 4; ++i)
#pragma unroll
        for (int j = 0; j < 4; ++j) acc[i][j] += av[i] * bv[j];
    }
  }
#pragma unroll
  for (int i = 0; i < 4; ++i) {
    int m = m0 + ty * 4 + i;
    float* crow = &C[(size_t)m * ldc + (n0 + tx * 4)];
    float4 v = make_float4(acc[i][0], acc[i][1], acc[i][2], acc[i][3]);
    if (bias) {
      const float* bp = &bias[n0 + tx * 4];
      v.x += bp[0]; v.y += bp[1]; v.z += bp[2]; v.w += bp[3];
    }
    *(float4*)crow = v;
  }
}

// ---------------- embedding: circular conv1d(k=3), split-store to h planes ----------------
__global__ __launch_bounds__(256) void embed_k(
    const float* __restrict__ x, const float* __restrict__ W, u16* __restrict__ Ch)
{
  __shared__ float As[TBK][TM + 4];
  __shared__ float Bs[TBK][TN + 4];
  const int t = threadIdx.x;
  const int m0 = blockIdx.x * TM, n0 = blockIdx.y * TN;
  const int tx = t & 15, ty = t >> 4;
  const int ar = t >> 2, akv = (t & 3) * 4;
  const int bkk = t >> 4, bc = (t & 15) * 4;
  const int m = m0 + ar, mb = m >> 10, ml = m & (L_ - 1);
  float acc[4][4] = {};
  for (int k0 = 0; k0 < 3 * CIN_; k0 += TBK) {
    int kcol = k0 + akv;
    int j = kcol >> 6, c = kcol & 63;
    int lsrc = (ml + j - 1 + L_) & (L_ - 1);
    float4 a4 = *(const float4*)&x[((size_t)mb * L_ + lsrc) * CIN_ + c];
    float4 w4 = *(const float4*)&W[(size_t)(k0 + bkk) * D_ + (n0 + bc)];
    __syncthreads();
    As[akv + 0][ar] = a4.x; As[akv + 1][ar] = a4.y;
    As[akv + 2][ar] = a4.z; As[akv + 3][ar] = a4.w;
    *(float4*)&Bs[bkk][bc] = w4;
    __syncthreads();
#pragma unroll
    for (int kk = 0; kk < TBK; ++kk) {
      float4 a = *(const float4*)&As[kk][ty * 4];
      float4 b = *(const float4*)&Bs[kk][tx * 4];
      float av[4] = {a.x, a.y, a.z, a.w};
      float bv[4] = {b.x, b.y, b.z, b.w};
#pragma unroll
      for (int i = 0; i < 4; ++i)
#pragma unroll
        for (int jj = 0; jj < 4; ++jj) acc[i][jj] += av[i] * bv[jj];
    }
  }
#pragma unroll
  for (int i = 0; i < 4; ++i) {
    int mm = m0 + ty * 4 + i;
    size_t ci = (size_t)mm * D_ + (n0 + tx * 4);
    ushort4 hv, lv;
    unsigned int s0 = split2(acc[i][0]), s1 = split2(acc[i][1]);
    unsigned int s2 = split2(acc[i][2]), s3 = split2(acc[i][3]);
    hv.x = (u16)s0; hv.y = (u16)s1; hv.z = (u16)s2; hv.w = (u16)s3;
    lv.x = (u16)(s0 >> 16); lv.y = (u16)(s1 >> 16); lv.z = (u16)(s2 >> 16); lv.w = (u16)(s3 >> 16);
    *(ushort4*)&Ch[ci] = hv;
    *(ushort4*)&Ch[ci + NBLD_] = lv;
  }
}

// ---------------- top-6 + softmax ----------------
__global__ __launch_bounds__(256) void topk_k(const float* __restrict__ mc,
                                              float* __restrict__ tc, int* __restrict__ dly)
{
  const int b = blockIdx.x, t = threadIdx.x;
  __shared__ float vals[L_];
  __shared__ float rv[256];
  __shared__ int ri[256];
  __shared__ float wsel[TOPK_];
  __shared__ int dsel[TOPK_];
  for (int i = t; i < L_; i += 256) vals[i] = mc[(size_t)b * L_ + i];
  __syncthreads();
  for (int kk = 0; kk < TOPK_; ++kk) {
    float bv = -INFINITY; int bi = 0x7fffffff;
    for (int i = t; i < L_; i += 256) {
      float v = vals[i];
      if (v > bv) { bv = v; bi = i; }
    }
    rv[t] = bv; ri[t] = bi;
    __syncthreads();
    for (int s = 128; s > 0; s >>= 1) {
      if (t < s) {
        if (rv[t + s] > rv[t] || (rv[t + s] == rv[t] && ri[t + s] < ri[t])) {
          rv[t] = rv[t + s]; ri[t] = ri[t + s];
        }
      }
      __syncthreads();
    }
    if (t == 0) { wsel[kk] = rv[0]; dsel[kk] = ri[0]; vals[ri[0]] = -INFINITY; }
    __syncthreads();
  }
  if (t == 0) {
    float m = wsel[0];
    float e[TOPK_], se = 0.f;
    for (int k = 0; k < TOPK_; ++k) { e[k] = expf(wsel[k] - m); se += e[k]; }
    for (int k = 0; k < TOPK_; ++k) {
      tc[b * TOPK_ + k] = e[k] / se;
      dly[b * TOPK_ + k] = dsel[k];
    }
  }
}

// ---------------- weighted delay-gather: fp32 V -> split out ----------------
__global__ __launch_bounds__(256) void gather_k(const float* __restrict__ v,
    const float* __restrict__ tc, const int* __restrict__ dly, u16* __restrict__ out)
{
  int tid = blockIdx.x * 256 + threadIdx.x;
  int c4 = tid & 127;
  int row = tid >> 7;
  int b = row >> 10, l = row & (L_ - 1);
  const float4* vb = (const float4*)(v + (size_t)b * L_ * D_);
  float4 o = make_float4(0.f, 0.f, 0.f, 0.f);
#pragma unroll
  for (int k = 0; k < TOPK_; ++k) {
    int ld = (l + dly[b * TOPK_ + k]) & (L_ - 1);
    float w = tc[b * TOPK_ + k];
    float4 vv = vb[(size_t)ld * (D_ / 4) + c4];
    o.x += w * vv.x; o.y += w * vv.y; o.z += w * vv.z; o.w += w * vv.w;
  }
  unsigned int s0 = split2(o.x), s1 = split2(o.y), s2 = split2(o.z), s3 = split2(o.w);
  ushort4 hv, lv;
  hv.x = (u16)s0; hv.y = (u16)s1; hv.z = (u16)s2; hv.w = (u16)s3;
  lv.x = (u16)(s0 >> 16); lv.y = (u16)(s1 >> 16); lv.z = (u16)(s2 >> 16); lv.w = (u16)(s3 >> 16);
  *(ushort4*)&out[(size_t)tid * 4] = hv;
  *(ushort4*)&out[(size_t)tid * 4 + NBLD_] = lv;
}

// ---------------- series decomposition: fp32 in -> split h out ----------------
__global__ __launch_bounds__(256) void decomp_k(const float* __restrict__ s,
                                                u16* __restrict__ outh)
{
  __shared__ float tile[152][64];
  const int t = threadIdx.x;
  const int l0 = blockIdx.x * 128, d0 = blockIdx.y * 64, b = blockIdx.z;
  const float* sb = s + (size_t)b * L_ * D_;
  for (int idx = t; idx < 152 * 16; idx += 256) {
    int row = idx >> 4, c4 = (idx & 15) * 4;
    int lsrc = l0 - 12 + row;
    lsrc = lsrc < 0 ? 0 : (lsrc > L_ - 1 ? L_ - 1 : lsrc);
    *(float4*)&tile[row][c4] = *(const float4*)&sb[(size_t)lsrc * D_ + d0 + c4];
  }
  __syncthreads();
  const int d = t & 63, lb = t >> 6;
  for (int it = 0; it < 32; ++it) {
    int lp = lb + it * 4;
    float sum = 0.f;
#pragma unroll
    for (int j = 0; j < 25; ++j) sum += tile[lp + j][d];
    float val = tile[lp + 12][d] - sum * (1.0f / 25.0f);
    unsigned int sp = split2(val);
    size_t ci = ((size_t)b * L_ + l0 + lp) * D_ + d0 + d;
    outh[ci] = (u16)(sp & 0xffffu);
    outh[ci + NBLD_] = (u16)(sp >> 16);
  }
}

// ---------------- LayerNorm over D (split h in, fp32 out) ----------------
__global__ __launch_bounds__(256) void ln_k(const u16* __restrict__ ah,
    const float* __restrict__ g, const float* __restrict__ be, float* __restrict__ out)
{
  __shared__ float red[256];
  const int row = blockIdx.x, t = threadIdx.x;
  const size_t base = (size_t)row * D_;
  float x0 = bf2f(ah[base + t]) + bf2f(ah[base + t + NBLD_]);
  float x1 = bf2f(ah[base + t + 256]) + bf2f(ah[base + t + 256 + NBLD_]);
  red[t] = x0 + x1;
  __syncthreads();
  for (int s = 128; s > 0; s >>= 1) { if (t < s) red[t] += red[t + s]; __syncthreads(); }
  float mu = red[0] * (1.0f / 512.0f);
  __syncthreads();
  float d0 = x0 - mu, d1 = x1 - mu;
  red[t] = d0 * d0 + d1 * d1;
  __syncthreads();
  for (int s = 128; s > 0; s >>= 1) { if (t < s) red[t] += red[t + s]; __syncthreads(); }
  float rs = rsqrtf(red[0] * (1.0f / 512.0f) + 1e-5f);
  out[base + t]       = d0 * rs * g[t] + be[t];
  out[base + t + 256] = d1 * rs * g[t + 256] + be[t + 256];
}

// ---------------- subtract per-(b,d) time mean over L ----------------
__global__ __launch_bounds__(256) void colmean_k(const float* __restrict__ a,
                                                 float* __restrict__ out)
{
  int tid = blockIdx.x * 256 + threadIdx.x;
  int b = tid >> 9, d = tid & (D_ - 1);
  const float* p = a + (size_t)b * L_ * D_ + d;
  float sum = 0.f;
  for (int l = 0; l < L_; ++l) sum += p[(size_t)l * D_];
  float mu = sum * (1.0f / 1024.0f);
  float* q = out + (size_t)b * L_ * D_ + d;
  for (int l = 0; l < L_; ++l) q[(size_t)l * D_] = p[(size_t)l * D_] - mu;
}

extern "C" void kernel_launch(void* const* d_in, const int* in_sizes, int n_in,
                              void* d_out, int out_size, void* d_ws, size_t ws_size,
                              hipStream_t stream) {
  (void)n_in; (void)in_sizes; (void)ws_size; (void)out_size;
  const float* x    = (const float*)d_in[0];
  const float* embw = (const float*)d_in[1];
  const float* wq   = (const float*)d_in[2];
  const float* bq   = (const float*)d_in[3];
  const float* wk   = (const float*)d_in[4];
  const float* bk   = (const float*)d_in[5];
  const float* wv   = (const float*)d_in[6];
  const float* bv   = (const float*)d_in[7];
  const float* wo   = (const float*)d_in[8];
  const float* bo   = (const float*)d_in[9];
  const float* w1   = (const float*)d_in[10];
  const float* w2   = (const float*)d_in[11];
  const float* lng  = (const float*)d_in[12];
  const float* lnb  = (const float*)d_in[13];
  const float* pw   = (const float*)d_in[14];
  const float* pb   = (const float*)d_in[15];

  const size_t nBLD = NBLD_;
  // h / t0 / t1 each occupy nBLD floats (= 2*nBLD u16 -> hi plane + lo plane)
  u16*   hh  = (u16*)d_ws;                       // h hi ; lo at +nBLD
  float* t0f = (float*)(hh + 2 * nBLD);
  u16*   t0h = (u16*)t0f;
  float* t1f = t0f + nBLD;
  u16*   t1h = (u16*)t1f;
  float* mcorr = t1f + nBLD;
  float* tc    = mcorr + (size_t)B_ * L_;
  int*   dly   = (int*)(tc + B_ * TOPK_);
  u16* base = (u16*)(dly + B_ * TOPK_ + 64);
  const size_t nDD = (size_t)NL_ * D_ * D_, nDF = (size_t)NL_ * D_ * DFF_;
  u16* wqTh = base;             u16* wqTl = wqTh + nDD;
  u16* wkTh = wqTl + nDD;       u16* wkTl = wkTh + nDD;
  u16* wvTh = wkTl + nDD;       u16* wvTl = wvTh + nDD;
  u16* woTh = wvTl + nDD;       u16* woTl = woTh + nDD;
  u16* w1Th = woTl + nDD;       u16* w1Tl = w1Th + nDF;
  u16* w2Th = w1Tl + nDF;       u16* w2Tl = w2Th + nDF;

  dim3 blk(256);
  const dim3 gGemm(512, 8);
  const dim3 gMfma(256, 4);
  const dim3 gCorr(8, 8, B_);

  for (int l = 0; l < NL_; ++l) {
    transp_split_k<<<dim3(16, 16), blk, 0, stream>>>(wq + (size_t)l * D_ * D_,
        wqTh + (size_t)l * D_ * D_, wqTl + (size_t)l * D_ * D_, D_, D_);
    transp_split_k<<<dim3(16, 16), blk, 0, stream>>>(wk + (size_t)l * D_ * D_,
        wkTh + (size_t)l * D_ * D_, wkTl + (size_t)l * D_ * D_, D_, D_);
    transp_split_k<<<dim3(16, 16), blk, 0, stream>>>(wv + (size_t)l * D_ * D_,
        wvTh + (size_t)l * D_ * D_, wvTl + (size_t)l * D_ * D_, D_, D_);
    transp_split_k<<<dim3(16, 16), blk, 0, stream>>>(wo + (size_t)l * D_ * D_,
        woTh + (size_t)l * D_ * D_, woTl + (size_t)l * D_ * D_, D_, D_);
    transp_split_k<<<dim3(16, 64), blk, 0, stream>>>(w1 + (size_t)l * D_ * DFF_,
        w1Th + (size_t)l * D_ * DFF_, w1Tl + (size_t)l * D_ * DFF_, D_, DFF_);
    transp_split_k<<<dim3(64, 16), blk, 0, stream>>>(w2 + (size_t)l * DFF_ * D_,
        w2Th + (size_t)l * DFF_ * D_, w2Tl + (size_t)l * DFF_ * D_, DFF_, D_);
  }

  embed_k<<<gGemm, blk, 0, stream>>>(x, embw, hh);

  for (int l = 0; l < NL_; ++l) {
    const bool last = (l == NL_ - 1);
    const size_t oDD = (size_t)l * D_ * D_;
    const u16* hl = hh + nBLD;

    // Q -> t0 planes, K -> t1 planes (split, mode 3)
    mfma_split_gemm_k<<<gMfma, blk, 0, stream>>>(hh, hl, D_, wqTh + oDD, wqTl + oDD, D_,
        t0h, D_, bq + (size_t)l * D_, nullptr, nullptr, D_, 3);
    mfma_split_gemm_k<<<gMfma, blk, 0, stream>>>(hh, hl, D_, wkTh + oDD, wkTl + oDD, D_,
        t1h, D_, bk + (size_t)l * D_, nullptr, nullptr, D_, 3);

    zero_k<<<dim3(128), blk, 0, stream>>>(mcorr, B_ * L_);
    corr_mfma_k<<<gCorr, blk, 0, stream>>>(t0h, t1h, mcorr);
    topk_k<<<dim3(B_), blk, 0, stream>>>(mcorr, tc, dly);

    // V -> t0f (fp32), gather -> t1 planes
    if (last)
      mfma_plain_gemm_k<<<gMfma, blk, 0, stream>>>(hh, D_, wvTh + oDD, D_,
          t0f, D_, bv + (size_t)l * D_, nullptr, nullptr, D_, 0);
    else
      mfma_split_gemm_k<<<gMfma, blk, 0, stream>>>(hh, hl, D_, wvTh + oDD, wvTl + oDD, D_,
          t0f, D_, bv + (size_t)l * D_, nullptr, nullptr, D_, 0);
    gather_k<<<dim3(16384), blk, 0, stream>>>(t0f, tc, dly, t1h);

    // out proj + bias + residual(h) -> t0f ; decomp -> h planes
    if (last)
      mfma_plain_gemm_k<<<gMfma, blk, 0, stream>>>(t1h, D_, woTh + oDD, D_,
          t0f, D_, bo + (size_t)l * D_, hh, hl, D_, 0);
    else
      mfma_split_gemm_k<<<gMfma, blk, 0, stream>>>(t1h, t1h + nBLD, D_, woTh + oDD, woTl + oDD, D_,
          t0f, D_, bo + (size_t)l * D_, hh, hl, D_, 0);
    decomp_k<<<dim3(8, 8, B_), blk, 0, stream>>>(t0f, hh);

    // FFN: 4 chunks; u -> t1 planes (gelu split), accumulate into t0f
    for (int c = 0; c < 4; ++c) {
      const u16* w1ch = w1Th + (size_t)l * D_ * DFF_ + (size_t)c * 512 * D_;
      const u16* w1cl = w1Tl + (size_t)l * D_ * DFF_ + (size_t)c * 512 * D_;
      const u16* w2ch = w2Th + (size_t)l * DFF_ * D_ + (size_t)c * 512;
      const u16* w2cl = w2Tl + (size_t)l * DFF_ * D_ + (size_t)c * 512;
      if (last) {
        mfma_plain_gemm_k<<<gMfma, blk, 0, stream>>>(hh, D_, w1ch, D_,
            t1h, D_, nullptr, nullptr, nullptr, D_, 1);
        if (c == 0)
          mfma_plain_gemm_k<<<gMfma, blk, 0, stream>>>(t1h, D_, w2ch, DFF_,
              t0f, D_, nullptr, hh, hl, D_, 0);
        else
          mfma_plain_gemm_k<<<gMfma, blk, 0, stream>>>(t1h, D_, w2ch, DFF_,
              t0f, D_, nullptr, nullptr, nullptr, D_, 2);
      } else {
        mfma_split_gemm_k<<<gMfma, blk, 0, stream>>>(hh, hl, D_, w1ch, w1cl, D_,
            t1h, D_, nullptr, nullptr, nullptr, D_, 1);
        if (c == 0)
          mfma_split_gemm_k<<<gMfma, blk, 0, stream>>>(t1h, t1h + nBLD, D_, w2ch, w2cl, DFF_,
              t0f, D_, nullptr, hh, hl, D_, 0);
        else
          mfma_split_gemm_k<<<gMfma, blk, 0, stream>>>(t1h, t1h + nBLD, D_, w2ch, w2cl, DFF_,
              t0f, D_, nullptr, nullptr, nullptr, D_, 2);
      }
    }
    decomp_k<<<dim3(8, 8, B_), blk, 0, stream>>>(t0f, hh);
  }

  ln_k<<<dim3(B_ * L_), blk, 0, stream>>>(hh, lng, lnb, t0f);
  colmean_k<<<dim3((B_ * D_) / 256), blk, 0, stream>>>(t0f, t1f);
  gemm_k<<<dim3(512, 1), blk, 0, stream>>>(t1f, D_, pw, CIN_, (float*)d_out, CIN_, pb, D_);
}

// Round 13
// 3806.729 us; speedup vs baseline: 1.2714x; 1.1703x over previous
//
#include <hip/hip_runtime.h>
#include <hip/hip_bf16.h>
#include <math.h>

#define B_   32
#define L_   1024
#define CIN_ 64
#define D_   512
#define DFF_ 2048
#define NL_  3
#define TOPK_ 6
#define NBLD_ ((size_t)B_ * L_ * D_)

#define TM 64
#define TN 64
#define TBK 16

typedef unsigned short u16;
typedef __bf16 bf16x8 __attribute__((ext_vector_type(8)));
typedef float  f32x4  __attribute__((ext_vector_type(4)));

typedef const __attribute__((address_space(1))) void* gp1_t;
typedef __attribute__((address_space(3))) void* lp3_t;

__device__ __forceinline__ void gll16(const void* g, void* l) {
  __builtin_amdgcn_global_load_lds((gp1_t)g, (lp3_t)l, 16, 0, 0);
}

__device__ __forceinline__ float bf2f(u16 u) {
  return __uint_as_float(((unsigned int)u) << 16);
}
__device__ __forceinline__ u16 f2bf(float f) {
  unsigned int u = __float_as_uint(f);
  return (u16)((u + 0x7fffu + ((u >> 16) & 1u)) >> 16);   // RNE
}
__device__ __forceinline__ unsigned int split2(float f) {
  u16 hi = f2bf(f);
  u16 lo = f2bf(f - bf2f(hi));
  return (unsigned int)hi | ((unsigned int)lo << 16);
}
__device__ __forceinline__ float gelu_f(float x) {
  return 0.5f * x * (1.0f + erff(x * 0.70710678118654752440f));
}

__global__ __launch_bounds__(256) void zero_k(float* __restrict__ p, int n) {
  int i = blockIdx.x * 256 + threadIdx.x;
  if (i < n) p[i] = 0.f;
}

// ---------------- weight transpose + bf16x2 split ----------------
__global__ __launch_bounds__(256) void transp_split_k(const float* __restrict__ W,
                                                      u16* __restrict__ WTh,
                                                      u16* __restrict__ WTl, int K, int N) {
  __shared__ float tile[32][33];
  const int t = threadIdx.x;
  const int k0 = blockIdx.x * 32, n0 = blockIdx.y * 32;
  const int tx = t & 31, ty = t >> 5;
#pragma unroll
  for (int i = 0; i < 4; ++i) {
    int kk = ty + i * 8;
    tile[kk][tx] = W[(size_t)(k0 + kk) * N + n0 + tx];
  }
  __syncthreads();
#pragma unroll
  for (int i = 0; i < 4; ++i) {
    int nn = ty + i * 8;
    unsigned int s = split2(tile[tx][nn]);
    WTh[(size_t)(n0 + nn) * K + k0 + tx] = (u16)(s & 0xffffu);
    WTl[(size_t)(n0 + nn) * K + k0 + tx] = (u16)(s >> 16);
  }
}

// ============ async split MFMA GEMM with vectorized LDS-bounce epilogue ============
// mode 0: +bias +R(hi/lo) -> fp32 ; 1: gelu -> split ; 2: fp32 += ; 3: +bias -> split
// grid.z==2 selects (W2,C2,bias2) for z=1 (merged Q/K launch).
__global__ __launch_bounds__(256) void mfma_split_gemm_k(
    const u16* __restrict__ Ah, const u16* __restrict__ Al, int lda,
    const u16* Wh, const u16* Wl, int ldwt,
    void* Cv, int ldc,
    const float* bias,
    const u16* __restrict__ Rh, const u16* __restrict__ Rl,
    int K, int mode,
    const u16* W2h, const u16* W2l, void* C2v, const float* bias2)
{
  if (blockIdx.z == 1) { Wh = W2h; Wl = W2l; Cv = C2v; bias = bias2; }
  __shared__ __align__(16) char smem[32768];
  u16* Ash = (u16*)smem;
  u16* Asl = Ash + 128 * 32;
  u16* Bsh = Asl + 128 * 32;
  u16* Bsl = Bsh + 128 * 32;
  const int t = threadIdx.x;
  const int m0 = blockIdx.x * 128, n0 = blockIdx.y * 128;
  const int lane = t & 63, w = t >> 6;
  const int lrow = lane >> 2, lq = lane & 3;
  const int qg8 = (lq ^ ((lrow >> 1) & 3)) * 8;
  const int wm = (w & 1) * 64, wn = (w >> 1) * 64;
  const int lm = lane & 15, quad = lane >> 4;
  const int kq8 = (quad ^ ((lm >> 1) & 3)) * 8;

  f32x4 acc[4][4];
#pragma unroll
  for (int i = 0; i < 4; ++i)
#pragma unroll
    for (int j = 0; j < 4; ++j) acc[i][j] = (f32x4){0.f, 0.f, 0.f, 0.f};

  for (int k0 = 0; k0 < K; k0 += 32) {
    __syncthreads();
#pragma unroll
    for (int seg = 0; seg < 2; ++seg) {
      const int r0 = w * 32 + seg * 16;
      const size_t ga = (size_t)(m0 + r0 + lrow) * lda + k0 + qg8;
      const size_t gb = (size_t)(n0 + r0 + lrow) * ldwt + k0 + qg8;
      gll16(Ah + ga, &Ash[r0 * 32]);
      gll16(Al + ga, &Asl[r0 * 32]);
      gll16(Wh + gb, &Bsh[r0 * 32]);
      gll16(Wl + gb, &Bsl[r0 * 32]);
    }
    __syncthreads();

    bf16x8 afh[4], afl[4], bfh[4], bfl[4];
#pragma unroll
    for (int mi = 0; mi < 4; ++mi) {
      afh[mi] = *(const bf16x8*)&Ash[(wm + mi * 16 + lm) * 32 + kq8];
      afl[mi] = *(const bf16x8*)&Asl[(wm + mi * 16 + lm) * 32 + kq8];
    }
#pragma unroll
    for (int ni = 0; ni < 4; ++ni) {
      bfh[ni] = *(const bf16x8*)&Bsh[(wn + ni * 16 + lm) * 32 + kq8];
      bfl[ni] = *(const bf16x8*)&Bsl[(wn + ni * 16 + lm) * 32 + kq8];
    }
#pragma unroll
    for (int mi = 0; mi < 4; ++mi)
#pragma unroll
      for (int ni = 0; ni < 4; ++ni) {
        acc[mi][ni] = __builtin_amdgcn_mfma_f32_16x16x32_bf16(afh[mi], bfh[ni], acc[mi][ni], 0, 0, 0);
        acc[mi][ni] = __builtin_amdgcn_mfma_f32_16x16x32_bf16(afh[mi], bfl[ni], acc[mi][ni], 0, 0, 0);
        acc[mi][ni] = __builtin_amdgcn_mfma_f32_16x16x32_bf16(afl[mi], bfh[ni], acc[mi][ni], 0, 0, 0);
      }
  }

  // -------- vectorized epilogue: per-wave LDS bounce (2 rounds of 32x64) --------
  float bcol[4];
#pragma unroll
  for (int ni = 0; ni < 4; ++ni)
    bcol[ni] = (bias && (mode == 0 || mode == 3)) ? bias[n0 + wn + ni * 16 + lm] : 0.f;
  __syncthreads();                       // all staging reads done before aliasing
  float* epi = (float*)smem + w * 2048;  // 8KB per wave
  float* Cf = (float*)Cv;
  u16* Cu = (u16*)Cv;
#pragma unroll
  for (int mi2 = 0; mi2 < 2; ++mi2) {
#pragma unroll
    for (int mm = 0; mm < 2; ++mm) {
      int mi = mi2 * 2 + mm;
#pragma unroll
      for (int ni = 0; ni < 4; ++ni)
#pragma unroll
        for (int r = 0; r < 4; ++r)
          epi[(mm * 16 + quad * 4 + r) * 64 + ni * 16 + lm] = acc[mi][ni][r] + bcol[ni];
    }
#pragma unroll
    for (int i = 0; i < 8; ++i) {
      int f = lane + 64 * i;
      int row = f >> 4, c4 = f & 15;
      int gr = m0 + wm + mi2 * 32 + row;
      int gc = n0 + wn + c4 * 4;
      size_t ci = (size_t)gr * ldc + gc;
      float4 v = *(const float4*)&epi[row * 64 + c4 * 4];
      if (mode == 0) {
        if (Rh) {
          ushort4 rh = *(const ushort4*)&Rh[ci];
          ushort4 rl = *(const ushort4*)&Rl[ci];
          v.x += bf2f(rh.x) + bf2f(rl.x); v.y += bf2f(rh.y) + bf2f(rl.y);
          v.z += bf2f(rh.z) + bf2f(rl.z); v.w += bf2f(rh.w) + bf2f(rl.w);
        }
        *(float4*)&Cf[ci] = v;
      } else if (mode == 2) {
        float4 o = *(const float4*)&Cf[ci];
        v.x += o.x; v.y += o.y; v.z += o.z; v.w += o.w;
        *(float4*)&Cf[ci] = v;
      } else {
        if (mode == 1) { v.x = gelu_f(v.x); v.y = gelu_f(v.y); v.z = gelu_f(v.z); v.w = gelu_f(v.w); }
        unsigned int s0 = split2(v.x), s1 = split2(v.y), s2 = split2(v.z), s3 = split2(v.w);
        ushort4 hv, lv;
        hv.x = (u16)s0; hv.y = (u16)s1; hv.z = (u16)s2; hv.w = (u16)s3;
        lv.x = (u16)(s0 >> 16); lv.y = (u16)(s1 >> 16); lv.z = (u16)(s2 >> 16); lv.w = (u16)(s3 >> 16);
        *(ushort4*)&Cu[ci] = hv;
        *(ushort4*)&Cu[ci + NBLD_] = lv;
      }
    }
  }
}

// ============ async plain bf16 MFMA GEMM (hi planes only, last layer) ============
__global__ __launch_bounds__(256) void mfma_plain_gemm_k(
    const u16* __restrict__ Ah, int lda,
    const u16* __restrict__ Wh, int ldwt,
    void* __restrict__ Cv, int ldc,
    const float* __restrict__ bias,
    const u16* __restrict__ Rh, const u16* __restrict__ Rl,
    int K, int mode)
{
  __shared__ __align__(16) char smem[32768];
  u16* Ash = (u16*)smem;
  u16* Bsh = Ash + 128 * 32;
  const int t = threadIdx.x;
  const int m0 = blockIdx.x * 128, n0 = blockIdx.y * 128;
  const int lane = t & 63, w = t >> 6;
  const int lrow = lane >> 2, lq = lane & 3;
  const int qg8 = (lq ^ ((lrow >> 1) & 3)) * 8;
  const int wm = (w & 1) * 64, wn = (w >> 1) * 64;
  const int lm = lane & 15, quad = lane >> 4;
  const int kq8 = (quad ^ ((lm >> 1) & 3)) * 8;

  f32x4 acc[4][4];
#pragma unroll
  for (int i = 0; i < 4; ++i)
#pragma unroll
    for (int j = 0; j < 4; ++j) acc[i][j] = (f32x4){0.f, 0.f, 0.f, 0.f};

  for (int k0 = 0; k0 < K; k0 += 32) {
    __syncthreads();
#pragma unroll
    for (int seg = 0; seg < 2; ++seg) {
      const int r0 = w * 32 + seg * 16;
      const size_t ga = (size_t)(m0 + r0 + lrow) * lda + k0 + qg8;
      const size_t gb = (size_t)(n0 + r0 + lrow) * ldwt + k0 + qg8;
      gll16(Ah + ga, &Ash[r0 * 32]);
      gll16(Wh + gb, &Bsh[r0 * 32]);
    }
    __syncthreads();

    bf16x8 af[4], bf[4];
#pragma unroll
    for (int mi = 0; mi < 4; ++mi)
      af[mi] = *(const bf16x8*)&Ash[(wm + mi * 16 + lm) * 32 + kq8];
#pragma unroll
    for (int ni = 0; ni < 4; ++ni)
      bf[ni] = *(const bf16x8*)&Bsh[(wn + ni * 16 + lm) * 32 + kq8];
#pragma unroll
    for (int mi = 0; mi < 4; ++mi)
#pragma unroll
      for (int ni = 0; ni < 4; ++ni)
        acc[mi][ni] = __builtin_amdgcn_mfma_f32_16x16x32_bf16(af[mi], bf[ni], acc[mi][ni], 0, 0, 0);
  }

  float bcol[4];
#pragma unroll
  for (int ni = 0; ni < 4; ++ni)
    bcol[ni] = (bias && (mode == 0 || mode == 3)) ? bias[n0 + wn + ni * 16 + lm] : 0.f;
  __syncthreads();
  float* epi = (float*)smem + w * 2048;
  float* Cf = (float*)Cv;
  u16* Cu = (u16*)Cv;
#pragma unroll
  for (int mi2 = 0; mi2 < 2; ++mi2) {
#pragma unroll
    for (int mm = 0; mm < 2; ++mm) {
      int mi = mi2 * 2 + mm;
#pragma unroll
      for (int ni = 0; ni < 4; ++ni)
#pragma unroll
        for (int r = 0; r < 4; ++r)
          epi[(mm * 16 + quad * 4 + r) * 64 + ni * 16 + lm] = acc[mi][ni][r] + bcol[ni];
    }
#pragma unroll
    for (int i = 0; i < 8; ++i) {
      int f = lane + 64 * i;
      int row = f >> 4, c4 = f & 15;
      int gr = m0 + wm + mi2 * 32 + row;
      int gc = n0 + wn + c4 * 4;
      size_t ci = (size_t)gr * ldc + gc;
      float4 v = *(const float4*)&epi[row * 64 + c4 * 4];
      if (mode == 0) {
        if (Rh) {
          ushort4 rh = *(const ushort4*)&Rh[ci];
          ushort4 rl = *(const ushort4*)&Rl[ci];
          v.x += bf2f(rh.x) + bf2f(rl.x); v.y += bf2f(rh.y) + bf2f(rl.y);
          v.z += bf2f(rh.z) + bf2f(rl.z); v.w += bf2f(rh.w) + bf2f(rl.w);
        }
        *(float4*)&Cf[ci] = v;
      } else if (mode == 2) {
        float4 o = *(const float4*)&Cf[ci];
        v.x += o.x; v.y += o.y; v.z += o.z; v.w += o.w;
        *(float4*)&Cf[ci] = v;
      } else {
        if (mode == 1) { v.x = gelu_f(v.x); v.y = gelu_f(v.y); v.z = gelu_f(v.z); v.w = gelu_f(v.w); }
        unsigned int s0 = split2(v.x), s1 = split2(v.y), s2 = split2(v.z), s3 = split2(v.w);
        ushort4 hv, lv;
        hv.x = (u16)s0; hv.y = (u16)s1; hv.z = (u16)s2; hv.w = (u16)s3;
        lv.x = (u16)(s0 >> 16); lv.y = (u16)(s1 >> 16); lv.z = (u16)(s2 >> 16); lv.w = (u16)(s3 >> 16);
        *(ushort4*)&Cu[ci] = hv;
        *(ushort4*)&Cu[ci + NBLD_] = lv;
      }
    }
  }
}

// ============ async split-MFMA Q.K^T with diagonal (mod-L) reduction ============
__global__ __launch_bounds__(256) void corr_mfma_k(
    const u16* __restrict__ q, const u16* __restrict__ kmat, float* __restrict__ mc)
{
  __shared__ u16 Ash[128 * 32];
  __shared__ u16 Asl[128 * 32];
  __shared__ u16 Bsh[128 * 32];
  __shared__ u16 Bsl[128 * 32];
  const int t = threadIdx.x;
  const int i0 = blockIdx.x * 128, j0 = blockIdx.y * 128, b = blockIdx.z;
  const int lane = t & 63, w = t >> 6;
  const int lrow = lane >> 2, lq = lane & 3;
  const int qg8 = (lq ^ ((lrow >> 1) & 3)) * 8;
  const int wm = (w & 1) * 64, wn = (w >> 1) * 64;
  const int lm = lane & 15, quad = lane >> 4;
  const int kq8 = (quad ^ ((lm >> 1) & 3)) * 8;

  f32x4 acc[4][4];
#pragma unroll
  for (int i = 0; i < 4; ++i)
#pragma unroll
    for (int j = 0; j < 4; ++j) acc[i][j] = (f32x4){0.f, 0.f, 0.f, 0.f};

  for (int k0 = 0; k0 < D_; k0 += 32) {
    __syncthreads();
#pragma unroll
    for (int seg = 0; seg < 2; ++seg) {
      const int r0 = w * 32 + seg * 16;
      const size_t ga = ((size_t)b * L_ + i0 + r0 + lrow) * D_ + k0 + qg8;
      const size_t gb = ((size_t)b * L_ + j0 + r0 + lrow) * D_ + k0 + qg8;
      gll16(q + ga, &Ash[r0 * 32]);
      gll16(q + ga + NBLD_, &Asl[r0 * 32]);
      gll16(kmat + gb, &Bsh[r0 * 32]);
      gll16(kmat + gb + NBLD_, &Bsl[r0 * 32]);
    }
    __syncthreads();

    bf16x8 afh[4], afl[4], bfh[4], bfl[4];
#pragma unroll
    for (int mi = 0; mi < 4; ++mi) {
      afh[mi] = *(const bf16x8*)&Ash[(wm + mi * 16 + lm) * 32 + kq8];
      afl[mi] = *(const bf16x8*)&Asl[(wm + mi * 16 + lm) * 32 + kq8];
    }
#pragma unroll
    for (int ni = 0; ni < 4; ++ni) {
      bfh[ni] = *(const bf16x8*)&Bsh[(wn + ni * 16 + lm) * 32 + kq8];
      bfl[ni] = *(const bf16x8*)&Bsl[(wn + ni * 16 + lm) * 32 + kq8];
    }
#pragma unroll
    for (int mi = 0; mi < 4; ++mi)
#pragma unroll
      for (int ni = 0; ni < 4; ++ni) {
        acc[mi][ni] = __builtin_amdgcn_mfma_f32_16x16x32_bf16(afh[mi], bfh[ni], acc[mi][ni], 0, 0, 0);
        acc[mi][ni] = __builtin_amdgcn_mfma_f32_16x16x32_bf16(afh[mi], bfl[ni], acc[mi][ni], 0, 0, 0);
        acc[mi][ni] = __builtin_amdgcn_mfma_f32_16x16x32_bf16(afl[mi], bfh[ni], acc[mi][ni], 0, 0, 0);
      }
  }

  __syncthreads();
  float* bins = (float*)Ash;
  if (t < 256) bins[t] = 0.f;
  __syncthreads();
#pragma unroll
  for (int mi = 0; mi < 4; ++mi)
#pragma unroll
    for (int ni = 0; ni < 4; ++ni) {
      int cj = wn + ni * 16 + lm;
#pragma unroll
      for (int r = 0; r < 4; ++r) {
        int ri = wm + mi * 16 + quad * 4 + r;
        atomicAdd(&bins[ri - cj + 127], acc[mi][ni][r]);
      }
    }
  __syncthreads();
  if (t < 255) {
    int tau = (i0 - j0 + t - 127 + 2 * L_) & (L_ - 1);
    atomicAdd(&mc[(size_t)b * L_ + tau], bins[t] * (1.0f / 512.0f));
  }
}

// ---------------- fp32 GEMM (final projection) ----------------
__global__ __launch_bounds__(256) void gemm_k(
    const float* __restrict__ A, int lda,
    const float* __restrict__ W, int ldw,
    float* __restrict__ C, int ldc,
    const float* __restrict__ bias,
    int K)
{
  __shared__ float As[TBK][TM + 4];
  __shared__ float Bs[TBK][TN + 4];
  const int t = threadIdx.x;
  const int m0 = blockIdx.x * TM;
  const int n0 = blockIdx.y * TN;
  const int tx = t & 15, ty = t >> 4;
  const int ar = t >> 2, akv = (t & 3) * 4;
  const int bkk = t >> 4, bc = (t & 15) * 4;
  float acc[4][4] = {};
  for (int k0 = 0; k0 < K; k0 += TBK) {
    float4 a4 = *(const float4*)&A[(size_t)(m0 + ar) * lda + (k0 + akv)];
    float4 w4 = *(const float4*)&W[(size_t)(k0 + bkk) * ldw + (n0 + bc)];
    __syncthreads();
    As[akv + 0][ar] = a4.x; As[akv + 1][ar] = a4.y;
    As[akv + 2][ar] = a4.z; As[akv + 3][ar] = a4.w;
    *(float4*)&Bs[bkk][bc] = w4;
    __syncthreads();
#pragma unroll
    for (int kk = 0; kk < TBK; ++kk) {
      float4 a = *(const float4*)&As[kk][ty * 4];
      float4 b = *(const float4*)&Bs[kk][tx * 4];
      float av[4] = {a.x, a.y, a.z, a.w};
      float bv[4] = {b.x, b.y, b.z, b.w};
#pragma unroll
      for (int i = 0; i < 4; ++i)
#pragma unroll
        for (int j = 0; j < 4; ++j) acc[i][j] += av[i] * bv[j];
    }
  }
#pragma unroll
  for (int i = 0; i < 4; ++i) {
    int m = m0 + ty * 4 + i;
    float* crow = &C[(size_t)m * ldc + (n0 + tx * 4)];
    float4 v = make_float4(acc[i][0], acc[i][1], acc[i][2], acc[i][3]);
    if (bias) {
      const float* bp = &bias[n0 + tx * 4];
      v.x += bp[0]; v.y += bp[1]; v.z += bp[2]; v.w += bp[3];
    }
    *(float4*)crow = v;
  }
}

// ---------------- embedding: circular conv1d(k=3), split-store to h planes ----------------
__global__ __launch_bounds__(256) void embed_k(
    const float* __restrict__ x, const float* __restrict__ W, u16* __restrict__ Ch)
{
  __shared__ float As[TBK][TM + 4];
  __shared__ float Bs[TBK][TN + 4];
  const int t = threadIdx.x;
  const int m0 = blockIdx.x * TM, n0 = blockIdx.y * TN;
  const int tx = t & 15, ty = t >> 4;
  const int ar = t >> 2, akv = (t & 3) * 4;
  const int bkk = t >> 4, bc = (t & 15) * 4;
  const int m = m0 + ar, mb = m >> 10, ml = m & (L_ - 1);
  float acc[4][4] = {};
  for (int k0 = 0; k0 < 3 * CIN_; k0 += TBK) {
    int kcol = k0 + akv;
    int j = kcol >> 6, c = kcol & 63;
    int lsrc = (ml + j - 1 + L_) & (L_ - 1);
    float4 a4 = *(const float4*)&x[((size_t)mb * L_ + lsrc) * CIN_ + c];
    float4 w4 = *(const float4*)&W[(size_t)(k0 + bkk) * D_ + (n0 + bc)];
    __syncthreads();
    As[akv + 0][ar] = a4.x; As[akv + 1][ar] = a4.y;
    As[akv + 2][ar] = a4.z; As[akv + 3][ar] = a4.w;
    *(float4*)&Bs[bkk][bc] = w4;
    __syncthreads();
#pragma unroll
    for (int kk = 0; kk < TBK; ++kk) {
      float4 a = *(const float4*)&As[kk][ty * 4];
      float4 b = *(const float4*)&Bs[kk][tx * 4];
      float av[4] = {a.x, a.y, a.z, a.w};
      float bv[4] = {b.x, b.y, b.z, b.w};
#pragma unroll
      for (int i = 0; i < 4; ++i)
#pragma unroll
        for (int jj = 0; jj < 4; ++jj) acc[i][jj] += av[i] * bv[jj];
    }
  }
#pragma unroll
  for (int i = 0; i < 4; ++i) {
    int mm = m0 + ty * 4 + i;
    size_t ci = (size_t)mm * D_ + (n0 + tx * 4);
    ushort4 hv, lv;
    unsigned int s0 = split2(acc[i][0]), s1 = split2(acc[i][1]);
    unsigned int s2 = split2(acc[i][2]), s3 = split2(acc[i][3]);
    hv.x = (u16)s0; hv.y = (u16)s1; hv.z = (u16)s2; hv.w = (u16)s3;
    lv.x = (u16)(s0 >> 16); lv.y = (u16)(s1 >> 16); lv.z = (u16)(s2 >> 16); lv.w = (u16)(s3 >> 16);
    *(ushort4*)&Ch[ci] = hv;
    *(ushort4*)&Ch[ci + NBLD_] = lv;
  }
}

// ---------------- top-6 + softmax ----------------
__global__ __launch_bounds__(256) void topk_k(const float* __restrict__ mc,
                                              float* __restrict__ tc, int* __restrict__ dly)
{
  const int b = blockIdx.x, t = threadIdx.x;
  __shared__ float vals[L_];
  __shared__ float rv[256];
  __shared__ int ri[256];
  __shared__ float wsel[TOPK_];
  __shared__ int dsel[TOPK_];
  for (int i = t; i < L_; i += 256) vals[i] = mc[(size_t)b * L_ + i];
  __syncthreads();
  for (int kk = 0; kk < TOPK_; ++kk) {
    float bv = -INFINITY; int bi = 0x7fffffff;
    for (int i = t; i < L_; i += 256) {
      float v = vals[i];
      if (v > bv) { bv = v; bi = i; }
    }
    rv[t] = bv; ri[t] = bi;
    __syncthreads();
    for (int s = 128; s > 0; s >>= 1) {
      if (t < s) {
        if (rv[t + s] > rv[t] || (rv[t + s] == rv[t] && ri[t + s] < ri[t])) {
          rv[t] = rv[t + s]; ri[t] = ri[t + s];
        }
      }
      __syncthreads();
    }
    if (t == 0) { wsel[kk] = rv[0]; dsel[kk] = ri[0]; vals[ri[0]] = -INFINITY; }
    __syncthreads();
  }
  if (t == 0) {
    float m = wsel[0];
    float e[TOPK_], se = 0.f;
    for (int k = 0; k < TOPK_; ++k) { e[k] = expf(wsel[k] - m); se += e[k]; }
    for (int k = 0; k < TOPK_; ++k) {
      tc[b * TOPK_ + k] = e[k] / se;
      dly[b * TOPK_ + k] = dsel[k];
    }
  }
}

// ---------------- weighted delay-gather: fp32 V -> split out ----------------
__global__ __launch_bounds__(256) void gather_k(const float* __restrict__ v,
    const float* __restrict__ tc, const int* __restrict__ dly, u16* __restrict__ out)
{
  int tid = blockIdx.x * 256 + threadIdx.x;
  int c4 = tid & 127;
  int row = tid >> 7;
  int b = row >> 10, l = row & (L_ - 1);
  const float4* vb = (const float4*)(v + (size_t)b * L_ * D_);
  float4 o = make_float4(0.f, 0.f, 0.f, 0.f);
#pragma unroll
  for (int k = 0; k < TOPK_; ++k) {
    int ld = (l + dly[b * TOPK_ + k]) & (L_ - 1);
    float w = tc[b * TOPK_ + k];
    float4 vv = vb[(size_t)ld * (D_ / 4) + c4];
    o.x += w * vv.x; o.y += w * vv.y; o.z += w * vv.z; o.w += w * vv.w;
  }
  unsigned int s0 = split2(o.x), s1 = split2(o.y), s2 = split2(o.z), s3 = split2(o.w);
  ushort4 hv, lv;
  hv.x = (u16)s0; hv.y = (u16)s1; hv.z = (u16)s2; hv.w = (u16)s3;
  lv.x = (u16)(s0 >> 16); lv.y = (u16)(s1 >> 16); lv.z = (u16)(s2 >> 16); lv.w = (u16)(s3 >> 16);
  *(ushort4*)&out[(size_t)tid * 4] = hv;
  *(ushort4*)&out[(size_t)tid * 4 + NBLD_] = lv;
}

// ---------------- series decomposition: fp32 in -> split h out ----------------
__global__ __launch_bounds__(256) void decomp_k(const float* __restrict__ s,
                                                u16* __restrict__ outh)
{
  __shared__ float tile[152][64];
  const int t = threadIdx.x;
  const int l0 = blockIdx.x * 128, d0 = blockIdx.y * 64, b = blockIdx.z;
  const float* sb = s + (size_t)b * L_ * D_;
  for (int idx = t; idx < 152 * 16; idx += 256) {
    int row = idx >> 4, c4 = (idx & 15) * 4;
    int lsrc = l0 - 12 + row;
    lsrc = lsrc < 0 ? 0 : (lsrc > L_ - 1 ? L_ - 1 : lsrc);
    *(float4*)&tile[row][c4] = *(const float4*)&sb[(size_t)lsrc * D_ + d0 + c4];
  }
  __syncthreads();
  const int d = t & 63, lb = t >> 6;
  for (int it = 0; it < 32; ++it) {
    int lp = lb + it * 4;
    float sum = 0.f;
#pragma unroll
    for (int j = 0; j < 25; ++j) sum += tile[lp + j][d];
    float val = tile[lp + 12][d] - sum * (1.0f / 25.0f);
    unsigned int sp = split2(val);
    size_t ci = ((size_t)b * L_ + l0 + lp) * D_ + d0 + d;
    outh[ci] = (u16)(sp & 0xffffu);
    outh[ci + NBLD_] = (u16)(sp >> 16);
  }
}

// ---------------- LayerNorm over D (split h in, fp32 out) ----------------
__global__ __launch_bounds__(256) void ln_k(const u16* __restrict__ ah,
    const float* __restrict__ g, const float* __restrict__ be, float* __restrict__ out)
{
  __shared__ float red[256];
  const int row = blockIdx.x, t = threadIdx.x;
  const size_t base = (size_t)row * D_;
  float x0 = bf2f(ah[base + t]) + bf2f(ah[base + t + NBLD_]);
  float x1 = bf2f(ah[base + t + 256]) + bf2f(ah[base + t + 256 + NBLD_]);
  red[t] = x0 + x1;
  __syncthreads();
  for (int s = 128; s > 0; s >>= 1) { if (t < s) red[t] += red[t + s]; __syncthreads(); }
  float mu = red[0] * (1.0f / 512.0f);
  __syncthreads();
  float d0 = x0 - mu, d1 = x1 - mu;
  red[t] = d0 * d0 + d1 * d1;
  __syncthreads();
  for (int s = 128; s > 0; s >>= 1) { if (t < s) red[t] += red[t + s]; __syncthreads(); }
  float rs = rsqrtf(red[0] * (1.0f / 512.0f) + 1e-5f);
  out[base + t]       = d0 * rs * g[t] + be[t];
  out[base + t + 256] = d1 * rs * g[t + 256] + be[t + 256];
}

// ---------------- subtract per-(b,d) time mean over L ----------------
__global__ __launch_bounds__(256) void colmean_k(const float* __restrict__ a,
                                                 float* __restrict__ out)
{
  int tid = blockIdx.x * 256 + threadIdx.x;
  int b = tid >> 9, d = tid & (D_ - 1);
  const float* p = a + (size_t)b * L_ * D_ + d;
  float sum = 0.f;
  for (int l = 0; l < L_; ++l) sum += p[(size_t)l * D_];
  float mu = sum * (1.0f / 1024.0f);
  float* q = out + (size_t)b * L_ * D_ + d;
  for (int l = 0; l < L_; ++l) q[(size_t)l * D_] = p[(size_t)l * D_] - mu;
}

extern "C" void kernel_launch(void* const* d_in, const int* in_sizes, int n_in,
                              void* d_out, int out_size, void* d_ws, size_t ws_size,
                              hipStream_t stream) {
  (void)n_in; (void)in_sizes; (void)ws_size; (void)out_size;
  const float* x    = (const float*)d_in[0];
  const float* embw = (const float*)d_in[1];
  const float* wq   = (const float*)d_in[2];
  const float* bq   = (const float*)d_in[3];
  const float* wk   = (const float*)d_in[4];
  const float* bk   = (const float*)d_in[5];
  const float* wv   = (const float*)d_in[6];
  const float* bv   = (const float*)d_in[7];
  const float* wo   = (const float*)d_in[8];
  const float* bo   = (const float*)d_in[9];
  const float* w1   = (const float*)d_in[10];
  const float* w2   = (const float*)d_in[11];
  const float* lng  = (const float*)d_in[12];
  const float* lnb  = (const float*)d_in[13];
  const float* pw   = (const float*)d_in[14];
  const float* pb   = (const float*)d_in[15];

  const size_t nBLD = NBLD_;
  u16*   hh  = (u16*)d_ws;                       // h hi ; lo at +nBLD
  float* t0f = (float*)(hh + 2 * nBLD);
  u16*   t0h = (u16*)t0f;
  float* t1f = t0f + nBLD;
  u16*   t1h = (u16*)t1f;
  float* mcorr = t1f + nBLD;
  float* tc    = mcorr + (size_t)B_ * L_;
  int*   dly   = (int*)(tc + B_ * TOPK_);
  u16* base = (u16*)(dly + B_ * TOPK_ + 64);
  const size_t nDD = (size_t)NL_ * D_ * D_, nDF = (size_t)NL_ * D_ * DFF_;
  u16* wqTh = base;             u16* wqTl = wqTh + nDD;
  u16* wkTh = wqTl + nDD;       u16* wkTl = wkTh + nDD;
  u16* wvTh = wkTl + nDD;       u16* wvTl = wvTh + nDD;
  u16* woTh = wvTl + nDD;       u16* woTl = woTh + nDD;
  u16* w1Th = woTl + nDD;       u16* w1Tl = w1Th + nDF;
  u16* w2Th = w1Tl + nDF;       u16* w2Tl = w2Th + nDF;

  dim3 blk(256);
  const dim3 gGemm(512, 8);
  const dim3 gMfma(256, 4);
  const dim3 gMfma2(256, 4, 2);    // merged Q/K
  const dim3 gCorr(8, 8, B_);

  for (int l = 0; l < NL_; ++l) {
    transp_split_k<<<dim3(16, 16), blk, 0, stream>>>(wq + (size_t)l * D_ * D_,
        wqTh + (size_t)l * D_ * D_, wqTl + (size_t)l * D_ * D_, D_, D_);
    transp_split_k<<<dim3(16, 16), blk, 0, stream>>>(wk + (size_t)l * D_ * D_,
        wkTh + (size_t)l * D_ * D_, wkTl + (size_t)l * D_ * D_, D_, D_);
    transp_split_k<<<dim3(16, 16), blk, 0, stream>>>(wv + (size_t)l * D_ * D_,
        wvTh + (size_t)l * D_ * D_, wvTl + (size_t)l * D_ * D_, D_, D_);
    transp_split_k<<<dim3(16, 16), blk, 0, stream>>>(wo + (size_t)l * D_ * D_,
        woTh + (size_t)l * D_ * D_, woTl + (size_t)l * D_ * D_, D_, D_);
    transp_split_k<<<dim3(16, 64), blk, 0, stream>>>(w1 + (size_t)l * D_ * DFF_,
        w1Th + (size_t)l * D_ * DFF_, w1Tl + (size_t)l * D_ * DFF_, D_, DFF_);
    transp_split_k<<<dim3(64, 16), blk, 0, stream>>>(w2 + (size_t)l * DFF_ * D_,
        w2Th + (size_t)l * DFF_ * D_, w2Tl + (size_t)l * DFF_ * D_, DFF_, D_);
  }

  embed_k<<<gGemm, blk, 0, stream>>>(x, embw, hh);

  for (int l = 0; l < NL_; ++l) {
    const bool last = (l == NL_ - 1);
    const size_t oDD = (size_t)l * D_ * D_;
    const u16* hl = hh + nBLD;

    // merged Q (z=0) and K (z=1) projections, split-store (mode 3)
    mfma_split_gemm_k<<<gMfma2, blk, 0, stream>>>(hh, hl, D_, wqTh + oDD, wqTl + oDD, D_,
        t0h, D_, bq + (size_t)l * D_, nullptr, nullptr, D_, 3,
        wkTh + oDD, wkTl + oDD, t1h, bk + (size_t)l * D_);

    zero_k<<<dim3(128), blk, 0, stream>>>(mcorr, B_ * L_);
    corr_mfma_k<<<gCorr, blk, 0, stream>>>(t0h, t1h, mcorr);
    topk_k<<<dim3(B_), blk, 0, stream>>>(mcorr, tc, dly);

    // V -> t0f (fp32), gather -> t1 planes
    if (last)
      mfma_plain_gemm_k<<<gMfma, blk, 0, stream>>>(hh, D_, wvTh + oDD, D_,
          t0f, D_, bv + (size_t)l * D_, nullptr, nullptr, D_, 0);
    else
      mfma_split_gemm_k<<<gMfma, blk, 0, stream>>>(hh, hl, D_, wvTh + oDD, wvTl + oDD, D_,
          t0f, D_, bv + (size_t)l * D_, nullptr, nullptr, D_, 0,
          nullptr, nullptr, nullptr, nullptr);
    gather_k<<<dim3(16384), blk, 0, stream>>>(t0f, tc, dly, t1h);

    // out proj + bias + residual(h) -> t0f ; decomp -> h planes
    if (last)
      mfma_plain_gemm_k<<<gMfma, blk, 0, stream>>>(t1h, D_, woTh + oDD, D_,
          t0f, D_, bo + (size_t)l * D_, hh, hl, D_, 0);
    else
      mfma_split_gemm_k<<<gMfma, blk, 0, stream>>>(t1h, t1h + nBLD, D_, woTh + oDD, woTl + oDD, D_,
          t0f, D_, bo + (size_t)l * D_, hh, hl, D_, 0,
          nullptr, nullptr, nullptr, nullptr);
    decomp_k<<<dim3(8, 8, B_), blk, 0, stream>>>(t0f, hh);

    // FFN: 4 chunks; u -> t1 planes (gelu split), accumulate into t0f
    for (int c = 0; c < 4; ++c) {
      const u16* w1ch = w1Th + (size_t)l * D_ * DFF_ + (size_t)c * 512 * D_;
      const u16* w1cl = w1Tl + (size_t)l * D_ * DFF_ + (size_t)c * 512 * D_;
      const u16* w2ch = w2Th + (size_t)l * DFF_ * D_ + (size_t)c * 512;
      const u16* w2cl = w2Tl + (size_t)l * DFF_ * D_ + (size_t)c * 512;
      if (last) {
        mfma_plain_gemm_k<<<gMfma, blk, 0, stream>>>(hh, D_, w1ch, D_,
            t1h, D_, nullptr, nullptr, nullptr, D_, 1);
        if (c == 0)
          mfma_plain_gemm_k<<<gMfma, blk, 0, stream>>>(t1h, D_, w2ch, DFF_,
              t0f, D_, nullptr, hh, hl, D_, 0);
        else
          mfma_plain_gemm_k<<<gMfma, blk, 0, stream>>>(t1h, D_, w2ch, DFF_,
              t0f, D_, nullptr, nullptr, nullptr, D_, 2);
      } else {
        mfma_split_gemm_k<<<gMfma, blk, 0, stream>>>(hh, hl, D_, w1ch, w1cl, D_,
            t1h, D_, nullptr, nullptr, nullptr, D_, 1,
            nullptr, nullptr, nullptr, nullptr);
        if (c == 0)
          mfma_split_gemm_k<<<gMfma, blk, 0, stream>>>(t1h, t1h + nBLD, D_, w2ch, w2cl, DFF_,
              t0f, D_, nullptr, hh, hl, D_, 0,
              nullptr, nullptr, nullptr, nullptr);
        else
          mfma_split_gemm_k<<<gMfma, blk, 0, stream>>>(t1h, t1h + nBLD, D_, w2ch, w2cl, DFF_,
              t0f, D_, nullptr, nullptr, nullptr, D_, 2,
              nullptr, nullptr, nullptr, nullptr);
      }
    }
    decomp_k<<<dim3(8, 8, B_), blk, 0, stream>>>(t0f, hh);
  }

  ln_k<<<dim3(B_ * L_), blk, 0, stream>>>(hh, lng, lnb, t0f);
  colmean_k<<<dim3((B_ * D_) / 256), blk, 0, stream>>>(t0f, t1f);
  gemm_k<<<dim3(512, 1), blk, 0, stream>>>(t1f, D_, pw, CIN_, (float*)d_out, CIN_, pb, D_);
}